// Round 2
// baseline (9000.699 us; speedup 1.0000x reference)
//
#include <hip/hip_runtime.h>
#include <hip/hip_bf16.h>
#include <math.h>

// Problem constants
static constexpr int Bv   = 2;
static constexpr int Tv   = 1024;
static constexpr int Cv   = 768;
static constexpr int Hv   = 12;
static constexpr int HSv  = 64;
static constexpr int Lv   = 4;
static constexpr int Vv   = 50257;
static constexpr int Mv   = Bv * Tv;          // 2048 rows
static constexpr float EPSv = 1e-6f;

// ---------------------------------------------------------------------------
// Embedding: x[b,t,:] = wte[idx[b,t],:] + wpe[t,:]
// ---------------------------------------------------------------------------
__global__ void embed_kernel(const int* __restrict__ idx,
                             const float* __restrict__ wte,
                             const float* __restrict__ wpe,
                             float* __restrict__ x) {
    int row = blockIdx.x;               // 0..2047 (= b*T + t)
    int t   = row & (Tv - 1);
    int tok = idx[row];
    const float* src = wte + (size_t)tok * Cv;
    const float* pos = wpe + (size_t)t * Cv;
    float* dst = x + (size_t)row * Cv;
    for (int c = threadIdx.x; c < Cv; c += 256)
        dst[c] = src[c] + pos[c];
}

// ---------------------------------------------------------------------------
// LayerNorm over last dim (768). One 256-thread block per row.
// ---------------------------------------------------------------------------
__global__ void ln_kernel(const float* __restrict__ in,
                          const float* __restrict__ sc,
                          const float* __restrict__ bi,
                          float* __restrict__ out) {
    int row = blockIdx.x;
    const float* xr = in + (size_t)row * Cv;
    int tid = threadIdx.x;
    float v0 = xr[tid];
    float v1 = xr[tid + 256];
    float v2 = xr[tid + 512];
    float sum = v0 + v1 + v2;
    float sq  = v0 * v0 + v1 * v1 + v2 * v2;
    #pragma unroll
    for (int off = 32; off; off >>= 1) {
        sum += __shfl_xor(sum, off, 64);
        sq  += __shfl_xor(sq,  off, 64);
    }
    __shared__ float ls[4], lq[4];
    int wave = tid >> 6, lane = tid & 63;
    if (lane == 0) { ls[wave] = sum; lq[wave] = sq; }
    __syncthreads();
    sum = ls[0] + ls[1] + ls[2] + ls[3];
    sq  = lq[0] + lq[1] + lq[2] + lq[3];
    float mean = sum * (1.0f / Cv);
    float var  = sq * (1.0f / Cv) - mean * mean;
    float rs   = rsqrtf(var + EPSv);
    float* orow = out + (size_t)row * Cv;
    orow[tid]       = (v0 - mean) * rs * sc[tid]       + bi[tid];
    orow[tid + 256] = (v1 - mean) * rs * sc[tid + 256] + bi[tid + 256];
    orow[tid + 512] = (v2 - mean) * rs * sc[tid + 512] + bi[tid + 512];
}

// ---------------------------------------------------------------------------
// Tiled fp32 GEMM: C[M,N] = A[M,K] @ B + epilogue
//   BT=false: B is [K,N] row-major.  BT=true: B is [N,K] row-major (wte).
//   EPI: 0 = +bias, 1 = +bias+residual, 2 = gelu(+bias), 3 = plain store, no bias
// 64x64 tile, BK=16, 256 threads, 4x4 accum per thread.
// ---------------------------------------------------------------------------
template<int EPI, bool BT>
__launch_bounds__(256)
__global__ void gemm_kernel(const float* __restrict__ A,
                            const float* __restrict__ B,
                            const float* __restrict__ bias,
                            const float* __restrict__ R,
                            float* __restrict__ C,
                            int M, int N, int K) {
    __shared__ float As[16][64];
    __shared__ float Bs[16][64];
    int tid = threadIdx.x;
    int rowBase = blockIdx.y * 64;
    int colBase = blockIdx.x * 64;
    int ty = tid >> 4, tx = tid & 15;
    int m0 = ty * 4, n0 = tx * 4;
    float acc[4][4] = {};

    int aRow = tid >> 2;            // 0..63
    int aK   = (tid & 3) * 4;       // 0,4,8,12
    int bK   = tid >> 4;            // 0..15
    int bN   = (tid & 15) * 4;      // 0..60
    int tN   = tid >> 2;            // 0..63 (BT)
    int tK   = (tid & 3) * 4;       // (BT)

    for (int k0 = 0; k0 < K; k0 += 16) {
        float4 av = *(const float4*)(A + (size_t)(rowBase + aRow) * K + k0 + aK);
        As[aK + 0][aRow] = av.x;
        As[aK + 1][aRow] = av.y;
        As[aK + 2][aRow] = av.z;
        As[aK + 3][aRow] = av.w;
        if (!BT) {
            float4 bv = *(const float4*)(B + (size_t)(k0 + bK) * N + colBase + bN);
            *(float4*)&Bs[bK][bN] = bv;
        } else {
            int n = colBase + tN;
            float4 bv = make_float4(0.f, 0.f, 0.f, 0.f);
            if (n < N) bv = *(const float4*)(B + (size_t)n * K + k0 + tK);
            Bs[tK + 0][tN] = bv.x;
            Bs[tK + 1][tN] = bv.y;
            Bs[tK + 2][tN] = bv.z;
            Bs[tK + 3][tN] = bv.w;
        }
        __syncthreads();
        #pragma unroll
        for (int k = 0; k < 16; ++k) {
            float4 a4 = *(const float4*)&As[k][m0];
            float4 b4 = *(const float4*)&Bs[k][n0];
            float aa[4] = {a4.x, a4.y, a4.z, a4.w};
            float bb[4] = {b4.x, b4.y, b4.z, b4.w};
            #pragma unroll
            for (int i = 0; i < 4; ++i)
                #pragma unroll
                for (int j = 0; j < 4; ++j)
                    acc[i][j] += aa[i] * bb[j];
        }
        __syncthreads();
    }

    #pragma unroll
    for (int i = 0; i < 4; ++i) {
        int row = rowBase + m0 + i;
        #pragma unroll
        for (int j = 0; j < 4; ++j) {
            int col = colBase + n0 + j;
            if (col >= N) continue;
            float v = acc[i][j];
            if (EPI == 0 || EPI == 1 || EPI == 2) v += bias[col];
            if (EPI == 1) v += R[(size_t)row * N + col];
            if (EPI == 2) {
                float u = v;
                float c = 0.7978845608028654f * (u + 0.044715f * u * u * u);
                v = 0.5f * u * (1.0f + tanhf(c));
            }
            C[(size_t)row * N + col] = v;
        }
    }
}

// ---------------------------------------------------------------------------
// Causal attention, one wave per query row, online softmax.
// qkv layout: [row=b*T+t][h*192 + {q:0..63, k:64..127, v:128..191}]
// out: [row][h*64 + d]
// ---------------------------------------------------------------------------
__global__ void attn_kernel(const float* __restrict__ qkv,
                            float* __restrict__ out) {
    int wave = threadIdx.x >> 6;
    int lane = threadIdx.x & 63;
    int r = blockIdx.x * 4 + wave;          // 0 .. B*H*T-1, r = (b*H+h)*T + t
    int b = r / (Hv * Tv);
    int h = (r / Tv) % Hv;
    int t = r & (Tv - 1);

    float q = qkv[((size_t)(b * Tv + t)) * (Hv * 192) + h * 192 + lane];
    float m = -INFINITY, l = 0.f, acc = 0.f;
    for (int s = 0; s <= t; ++s) {
        const float* kv = qkv + ((size_t)(b * Tv + s)) * (Hv * 192) + h * 192;
        float p = q * kv[64 + lane];
        #pragma unroll
        for (int off = 32; off; off >>= 1) p += __shfl_xor(p, off, 64);
        float score = p * 0.125f;           // 1/sqrt(64)
        float mn = fmaxf(m, score);
        float e  = __expf(score - mn);
        float cr = __expf(m - mn);
        float vd = kv[128 + lane];
        l   = l * cr + e;
        acc = acc * cr + e * vd;
        m = mn;
    }
    out[(size_t)(b * Tv + t) * Cv + h * 64 + lane] = acc / l;
}

// ---------------------------------------------------------------------------
// Loss part 1: per-row logsumexp over V (fp32 logits) minus target logit.
// ---------------------------------------------------------------------------
__global__ void loss_rows_kernel(const float* __restrict__ logits,
                                 const int* __restrict__ targets,
                                 float* __restrict__ rloss) {
    int row = blockIdx.x;
    const float* lr = logits + (size_t)row * Vv;
    float m = -INFINITY, l = 0.f;
    for (int i = threadIdx.x; i < Vv; i += 256) {
        float v = lr[i];
        float mn = fmaxf(m, v);
        l = l * __expf(m - mn) + __expf(v - mn);
        m = mn;
    }
    #pragma unroll
    for (int off = 32; off; off >>= 1) {
        float m2 = __shfl_xor(m, off, 64);
        float l2 = __shfl_xor(l, off, 64);
        float mn = fmaxf(m, m2);
        l = l * __expf(m - mn) + l2 * __expf(m2 - mn);
        m = mn;
    }
    __shared__ float sm[4], sl[4];
    int wave = threadIdx.x >> 6, lane = threadIdx.x & 63;
    if (lane == 0) { sm[wave] = m; sl[wave] = l; }
    __syncthreads();
    if (threadIdx.x == 0) {
        float mm = sm[0], ll = sl[0];
        #pragma unroll
        for (int w = 1; w < 4; ++w) {
            float mn = fmaxf(mm, sm[w]);
            ll = ll * __expf(mm - mn) + sl[w] * __expf(sm[w] - mn);
            mm = mn;
        }
        float lse = mm + logf(ll);
        float lt  = lr[targets[row]];
        rloss[row] = lse - lt;
    }
}

__global__ void loss_final_kernel(const float* __restrict__ rloss,
                                  float* __restrict__ out,
                                  int out_size) {
    float s = 0.f;
    for (int i = threadIdx.x; i < Mv; i += 256) s += rloss[i];
    #pragma unroll
    for (int off = 32; off; off >>= 1) s += __shfl_xor(s, off, 64);
    __shared__ float sw[4];
    int wave = threadIdx.x >> 6, lane = threadIdx.x & 63;
    if (lane == 0) sw[wave] = s;
    __syncthreads();
    if (threadIdx.x == 0) {
        float tot = sw[0] + sw[1] + sw[2] + sw[3];
        out[out_size - 1] = tot / (float)Mv;
    }
}

// ---------------------------------------------------------------------------
extern "C" void kernel_launch(void* const* d_in, const int* in_sizes, int n_in,
                              void* d_out, int out_size, void* d_ws, size_t ws_size,
                              hipStream_t stream) {
    const int*   idx     = (const int*)  d_in[0];
    const int*   targets = (const int*)  d_in[1];
    const float* wte     = (const float*)d_in[2];
    const float* wpe     = (const float*)d_in[3];
    const float* ln1_s   = (const float*)d_in[4];
    const float* ln1_b   = (const float*)d_in[5];
    const float* attn_k  = (const float*)d_in[6];
    const float* attn_b  = (const float*)d_in[7];
    const float* aproj_k = (const float*)d_in[8];
    const float* aproj_b = (const float*)d_in[9];
    const float* ln2_s   = (const float*)d_in[10];
    const float* ln2_b   = (const float*)d_in[11];
    const float* fc_k    = (const float*)d_in[12];
    const float* fc_b    = (const float*)d_in[13];
    const float* mproj_k = (const float*)d_in[14];
    const float* mproj_b = (const float*)d_in[15];
    const float* lnf_s   = (const float*)d_in[16];
    const float* lnf_b   = (const float*)d_in[17];

    float* out = (float*)d_out;
    float* ws = (float*)d_ws;

    // workspace layout (floats)
    float* x     = ws;                       // 2048*768
    float* h     = ws + 1572864;             // 2048*768
    float* qkv   = ws + 3145728;             // 2048*2304
    float* att   = ws + 7864320;             // 2048*768
    float* fco   = ws + 9437184;             // 2048*3072
    float* rloss = ws + 15728640;            // 2048

    embed_kernel<<<Mv, 256, 0, stream>>>(idx, wte, wpe, x);

    for (int l = 0; l < Lv; ++l) {
        ln_kernel<<<Mv, 256, 0, stream>>>(x, ln1_s + l * Cv, ln1_b + l * Cv, h);
        gemm_kernel<0, false><<<dim3(36, 32), 256, 0, stream>>>(
            h, attn_k + (size_t)l * Cv * 2304, attn_b + l * 2304, nullptr,
            qkv, Mv, 2304, Cv);
        attn_kernel<<<Bv * Hv * Tv / 4, 256, 0, stream>>>(qkv, att);
        gemm_kernel<1, false><<<dim3(12, 32), 256, 0, stream>>>(
            att, aproj_k + (size_t)l * Cv * Cv, aproj_b + l * Cv, x,
            x, Mv, Cv, Cv);
        ln_kernel<<<Mv, 256, 0, stream>>>(x, ln2_s + l * Cv, ln2_b + l * Cv, h);
        gemm_kernel<2, false><<<dim3(48, 32), 256, 0, stream>>>(
            h, fc_k + (size_t)l * Cv * 3072, fc_b + l * 3072, nullptr,
            fco, Mv, 3072, Cv);
        gemm_kernel<1, false><<<dim3(12, 32), 256, 0, stream>>>(
            fco, mproj_k + (size_t)l * 3072 * Cv, mproj_b + l * Cv, x,
            x, Mv, Cv, 3072);
    }

    ln_kernel<<<Mv, 256, 0, stream>>>(x, lnf_s, lnf_b, h);
    // lm head: logits[m,v] = h[m,:] . wte[v,:]  (BT gemm), fp32 store to d_out
    gemm_kernel<3, true><<<dim3((Vv + 63) / 64, 32), 256, 0, stream>>>(
        h, wte, nullptr, nullptr, out, Mv, Vv, Cv);

    loss_rows_kernel<<<Mv, 256, 0, stream>>>(out, targets, rloss);
    loss_final_kernel<<<1, 256, 0, stream>>>(rloss, out, out_size);
}

// Round 3
// 2098.650 us; speedup vs baseline: 4.2888x; 4.2888x over previous
//
#include <hip/hip_runtime.h>
#include <hip/hip_bf16.h>
#include <math.h>

typedef __attribute__((ext_vector_type(8))) short bf16x8;
typedef __attribute__((ext_vector_type(4))) float f32x4;

static constexpr int Bv   = 2;
static constexpr int Tv   = 1024;
static constexpr int Cv   = 768;
static constexpr int Hv   = 12;
static constexpr int Lv   = 4;
static constexpr int Vv   = 50257;
static constexpr int Mv   = 2048;
static constexpr float EPSv = 1e-6f;

// ---------------------------------------------------------------------------
__device__ __forceinline__ void gload16(const void* g, void* l) {
    __builtin_amdgcn_global_load_lds((const __attribute__((address_space(1))) void*)g,
                                     (__attribute__((address_space(3))) void*)l, 16, 0, 0);
}

// ---------------------------------------------------------------------------
// Embedding: x[b,t,:] = wte[idx[b,t],:] + wpe[t,:]   (fp32)
// ---------------------------------------------------------------------------
__global__ void embed_kernel(const int* __restrict__ idx,
                             const float* __restrict__ wte,
                             const float* __restrict__ wpe,
                             float* __restrict__ x) {
    int row = blockIdx.x;
    int t   = row & (Tv - 1);
    int tok = idx[row];
    const float* src = wte + (size_t)tok * Cv;
    const float* pos = wpe + (size_t)t * Cv;
    float* dst = x + (size_t)row * Cv;
    for (int c = threadIdx.x; c < Cv; c += 256)
        dst[c] = src[c] + pos[c];
}

// ---------------------------------------------------------------------------
// LayerNorm fp32 in -> bf16 out. One 256-thread block per row.
// ---------------------------------------------------------------------------
__global__ void ln_kernel(const float* __restrict__ in,
                          const float* __restrict__ sc,
                          const float* __restrict__ bi,
                          __hip_bfloat16* __restrict__ out) {
    int row = blockIdx.x;
    const float* xr = in + (size_t)row * Cv;
    int tid = threadIdx.x;
    float v0 = xr[tid];
    float v1 = xr[tid + 256];
    float v2 = xr[tid + 512];
    float sum = v0 + v1 + v2;
    float sq  = v0 * v0 + v1 * v1 + v2 * v2;
    #pragma unroll
    for (int off = 32; off; off >>= 1) {
        sum += __shfl_xor(sum, off, 64);
        sq  += __shfl_xor(sq,  off, 64);
    }
    __shared__ float ls[4], lq[4];
    int wave = tid >> 6, lane = tid & 63;
    if (lane == 0) { ls[wave] = sum; lq[wave] = sq; }
    __syncthreads();
    sum = ls[0] + ls[1] + ls[2] + ls[3];
    sq  = lq[0] + lq[1] + lq[2] + lq[3];
    float mean = sum * (1.0f / Cv);
    float var  = sq * (1.0f / Cv) - mean * mean;
    float rs   = rsqrtf(var + EPSv);
    __hip_bfloat16* orow = out + (size_t)row * Cv;
    orow[tid]       = __float2bfloat16((v0 - mean) * rs * sc[tid]       + bi[tid]);
    orow[tid + 256] = __float2bfloat16((v1 - mean) * rs * sc[tid + 256] + bi[tid + 256]);
    orow[tid + 512] = __float2bfloat16((v2 - mean) * rs * sc[tid + 512] + bi[tid + 512]);
}

// ---------------------------------------------------------------------------
// Weight transpose+convert: in fp32 [K][N] -> out bf16 [N][K]
// ---------------------------------------------------------------------------
__global__ void wtrans_kernel(const float* __restrict__ in,
                              __hip_bfloat16* __restrict__ out, int K, int N) {
    __shared__ float tile[32][33];
    int k0 = blockIdx.y * 32, n0 = blockIdx.x * 32;
    int tx = threadIdx.x & 31, ty = threadIdx.x >> 5;   // 32 x 8
    #pragma unroll
    for (int i = 0; i < 4; ++i)
        tile[ty + i * 8][tx] = in[(size_t)(k0 + ty + i * 8) * N + n0 + tx];
    __syncthreads();
    #pragma unroll
    for (int i = 0; i < 4; ++i)
        out[(size_t)(n0 + ty + i * 8) * K + k0 + tx] =
            __float2bfloat16(tile[tx][ty + i * 8]);
}

// ---------------------------------------------------------------------------
// Straight fp32 -> bf16 convert (wte), float4 granularity, grid-stride.
// ---------------------------------------------------------------------------
__global__ void cvt_kernel(const float* __restrict__ in,
                           __hip_bfloat16* __restrict__ out, int n4) {
    int stride = gridDim.x * 256;
    for (int i = blockIdx.x * 256 + threadIdx.x; i < n4; i += stride) {
        float4 v = ((const float4*)in)[i];
        ushort4 u;
        u.x = __bfloat16_as_ushort(__float2bfloat16(v.x));
        u.y = __bfloat16_as_ushort(__float2bfloat16(v.y));
        u.z = __bfloat16_as_ushort(__float2bfloat16(v.z));
        u.w = __bfloat16_as_ushort(__float2bfloat16(v.w));
        ((ushort4*)out)[i] = u;
    }
}

// ---------------------------------------------------------------------------
// bf16 MFMA GEMM (m97 structure): C[M,N] = A[M,K] @ Bt[N,K]^T + epilogue
// 128x128 tile, BK=32, 256 threads (4 waves, 2x2), 4x4 16x16x32 frags/wave.
//   EPI 0: Cf = acc + bias                (fp32 out)
//   EPI 1: Cf = acc + bias + R  (R==Cf ok, in-place residual; fp32 out)
//   EPI 2: Cb = bf16(gelu(acc + bias))    (bf16 out)
//   EPI 3: Cf = acc                       (fp32 out, col<N guard; lm head)
// ---------------------------------------------------------------------------
template<int EPI>
__launch_bounds__(256)
__global__ void gemm_bf16(const __hip_bfloat16* __restrict__ A,
                          const __hip_bfloat16* __restrict__ Bt,
                          const float* __restrict__ bias,
                          const float* R, float* Cf,
                          __hip_bfloat16* __restrict__ Cb,
                          int M, int N, int K) {
    __shared__ __hip_bfloat16 As[128 * 32];
    __shared__ __hip_bfloat16 Bs[128 * 32];
    int tid = threadIdx.x;
    int wave = tid >> 6, lane = tid & 63;
    int wr = wave >> 1, wc = wave & 1;
    int rowBase = blockIdx.y * 128, colBase = blockIdx.x * 128;

    f32x4 acc[4][4] = {};

    // staging: per call each wave fills 16 rows (lane l -> row w*16+(l>>2), k (l&3)*8)
    int srow  = wave * 16 + (lane >> 2);
    int skcol = (lane & 3) * 8;
    const __hip_bfloat16* Ap  = A  + (size_t)(rowBase + srow) * K + skcol;
    const __hip_bfloat16* Ap2 = Ap + (size_t)64 * K;
    const __hip_bfloat16* Bp  = Bt + (size_t)(colBase + srow) * K + skcol;
    const __hip_bfloat16* Bp2 = Bp + (size_t)64 * K;
    __hip_bfloat16* AsW  = &As[wave * 512];
    __hip_bfloat16* AsW2 = &As[2048 + wave * 512];
    __hip_bfloat16* BsW  = &Bs[wave * 512];
    __hip_bfloat16* BsW2 = &Bs[2048 + wave * 512];

    int aoff = (wr * 64 + (lane & 15)) * 32 + (lane >> 4) * 8;
    int boff = (wc * 64 + (lane & 15)) * 32 + (lane >> 4) * 8;

    for (int k0 = 0; k0 < K; k0 += 32) {
        gload16(Ap,  AsW);
        gload16(Ap2, AsW2);
        gload16(Bp,  BsW);
        gload16(Bp2, BsW2);
        Ap += 32; Ap2 += 32; Bp += 32; Bp2 += 32;
        __syncthreads();                      // vmcnt(0) drain + barrier

        bf16x8 av[4], bv[4];
        #pragma unroll
        for (int m = 0; m < 4; ++m)
            av[m] = *(const bf16x8*)&As[aoff + m * 16 * 32];
        #pragma unroll
        for (int n = 0; n < 4; ++n)
            bv[n] = *(const bf16x8*)&Bs[boff + n * 16 * 32];
        #pragma unroll
        for (int m = 0; m < 4; ++m)
            #pragma unroll
            for (int n = 0; n < 4; ++n)
                acc[m][n] = __builtin_amdgcn_mfma_f32_16x16x32_bf16(
                    av[m], bv[n], acc[m][n], 0, 0, 0);
        __syncthreads();                      // all waves done reading LDS
    }

    int fq = lane >> 4, fr = lane & 15;
    #pragma unroll
    for (int m = 0; m < 4; ++m) {
        #pragma unroll
        for (int n = 0; n < 4; ++n) {
            f32x4 v = acc[m][n];
            int col = colBase + wc * 64 + n * 16 + fr;
            if (col >= N) continue;
            #pragma unroll
            for (int j = 0; j < 4; ++j) {
                int row = rowBase + wr * 64 + m * 16 + fq * 4 + j;
                float val = v[j];
                if (EPI == 0 || EPI == 1 || EPI == 2) val += bias[col];
                if (EPI == 1) val += R[(size_t)row * N + col];
                if (EPI == 2) {
                    float u = val;
                    float c = 0.7978845608028654f * (u + 0.044715f * u * u * u);
                    val = 0.5f * u * (1.0f + tanhf(c));
                    Cb[(size_t)row * N + col] = __float2bfloat16(val);
                } else {
                    Cf[(size_t)row * N + col] = val;
                }
            }
        }
    }
}

// ---------------------------------------------------------------------------
// Tiled causal attention, fp32 compute, bf16 out.
// grid (T/16, B*H), 256 threads = 4 waves; wave handles 4 q-rows.
// qkv[row][h*192 + {q:0,k:64,v:128} + d], out[row][h*64+d] (bf16)
// ---------------------------------------------------------------------------
__launch_bounds__(256)
__global__ void attn_kernel(const float* __restrict__ qkv,
                            __hip_bfloat16* __restrict__ att) {
    __shared__ float Kt[64][65];      // Kt[d][s]
    __shared__ float Vs[64][68];      // Vs[s][d]
    __shared__ float qs[16][64];
    __shared__ float ps[4][4][64];
    int bh = blockIdx.y;
    int b = bh / Hv, h = bh % Hv;
    int q0 = blockIdx.x * 16;
    int wave = threadIdx.x >> 6, lane = threadIdx.x & 63;
    const float* base = qkv + (size_t)b * Tv * 2304 + h * 192;

    {   // stage q rows
        int r = threadIdx.x >> 4;
        int d = (threadIdx.x & 15) * 4;
        float4 v = *(const float4*)(base + (size_t)(q0 + r) * 2304 + d);
        *(float4*)&qs[r][d] = v;
    }

    float acc[4]  = {0.f, 0.f, 0.f, 0.f};
    float mrow[4] = {-3.4e38f, -3.4e38f, -3.4e38f, -3.4e38f};
    float lrow[4] = {0.f, 0.f, 0.f, 0.f};
    int qrow = wave * 4;
    int nt = (q0 >> 6) + 1;

    for (int tix = 0; tix < nt; ++tix) {
        int s0 = tix * 64;
        __syncthreads();
        {   // stage K (transposed) and V
            int s  = threadIdx.x >> 2;
            int dg = (threadIdx.x & 3) * 16;
            const float* krow = base + (size_t)(s0 + s) * 2304 + 64;
            #pragma unroll
            for (int i = 0; i < 4; ++i) {
                float4 v = *(const float4*)(krow + dg + i * 4);
                Kt[dg + i * 4 + 0][s] = v.x;
                Kt[dg + i * 4 + 1][s] = v.y;
                Kt[dg + i * 4 + 2][s] = v.z;
                Kt[dg + i * 4 + 3][s] = v.w;
            }
            const float* vrow = krow + 64;
            #pragma unroll
            for (int i = 0; i < 4; ++i)
                *(float4*)&Vs[s][dg + i * 4] = *(const float4*)(vrow + dg + i * 4);
        }
        __syncthreads();

        // phase 1: lane = key index
        float sc[4] = {0.f, 0.f, 0.f, 0.f};
        #pragma unroll 4
        for (int d = 0; d < 64; d += 4) {
            float k0v = Kt[d + 0][lane];
            float k1v = Kt[d + 1][lane];
            float k2v = Kt[d + 2][lane];
            float k3v = Kt[d + 3][lane];
            #pragma unroll
            for (int r = 0; r < 4; ++r) {
                float4 q4 = *(const float4*)&qs[qrow + r][d];
                sc[r] += q4.x * k0v + q4.y * k1v + q4.z * k2v + q4.w * k3v;
            }
        }

        float crs[4];
        #pragma unroll
        for (int r = 0; r < 4; ++r) {
            int trow = q0 + qrow + r;
            bool valid = (s0 + lane) <= trow;
            float sv = valid ? sc[r] * 0.125f : -3.4e38f;
            float mx = sv;
            #pragma unroll
            for (int off = 32; off; off >>= 1) mx = fmaxf(mx, __shfl_xor(mx, off, 64));
            float mnew = fmaxf(mrow[r], mx);
            float p = valid ? __expf(sc[r] * 0.125f - mnew) : 0.f;
            float sum = p;
            #pragma unroll
            for (int off = 32; off; off >>= 1) sum += __shfl_xor(sum, off, 64);
            crs[r] = __expf(mrow[r] - mnew);
            lrow[r] = lrow[r] * crs[r] + sum;
            mrow[r] = mnew;
            ps[wave][r][lane] = p;
        }

        // phase 2: lane = head dim
        #pragma unroll
        for (int r = 0; r < 4; ++r) acc[r] *= crs[r];
        #pragma unroll 4
        for (int j = 0; j < 64; j += 4) {
            float4 p0 = *(const float4*)&ps[wave][0][j];
            float4 p1 = *(const float4*)&ps[wave][1][j];
            float4 p2 = *(const float4*)&ps[wave][2][j];
            float4 p3 = *(const float4*)&ps[wave][3][j];
            float v0 = Vs[j + 0][lane];
            float v1 = Vs[j + 1][lane];
            float v2 = Vs[j + 2][lane];
            float v3 = Vs[j + 3][lane];
            acc[0] += p0.x * v0 + p0.y * v1 + p0.z * v2 + p0.w * v3;
            acc[1] += p1.x * v0 + p1.y * v1 + p1.z * v2 + p1.w * v3;
            acc[2] += p2.x * v0 + p2.y * v1 + p2.z * v2 + p2.w * v3;
            acc[3] += p3.x * v0 + p3.y * v1 + p3.z * v2 + p3.w * v3;
        }
    }

    #pragma unroll
    for (int r = 0; r < 4; ++r)
        att[(size_t)(b * Tv + q0 + qrow + r) * Cv + h * 64 + lane] =
            __float2bfloat16(acc[r] / lrow[r]);
}

// ---------------------------------------------------------------------------
// Loss: per-row logsumexp over V minus target logit; then mean.
// ---------------------------------------------------------------------------
__global__ void loss_rows_kernel(const float* __restrict__ logits,
                                 const int* __restrict__ targets,
                                 float* __restrict__ rloss) {
    int row = blockIdx.x;
    const float* lr = logits + (size_t)row * Vv;
    float m = -INFINITY, l = 0.f;
    for (int i = threadIdx.x; i < Vv; i += 256) {
        float v = lr[i];
        float mn = fmaxf(m, v);
        l = l * __expf(m - mn) + __expf(v - mn);
        m = mn;
    }
    #pragma unroll
    for (int off = 32; off; off >>= 1) {
        float m2 = __shfl_xor(m, off, 64);
        float l2 = __shfl_xor(l, off, 64);
        float mn = fmaxf(m, m2);
        l = l * __expf(m - mn) + l2 * __expf(m2 - mn);
        m = mn;
    }
    __shared__ float sm[4], sl[4];
    int wave = threadIdx.x >> 6, lane = threadIdx.x & 63;
    if (lane == 0) { sm[wave] = m; sl[wave] = l; }
    __syncthreads();
    if (threadIdx.x == 0) {
        float mm = sm[0], ll = sl[0];
        #pragma unroll
        for (int w = 1; w < 4; ++w) {
            float mn = fmaxf(mm, sm[w]);
            ll = ll * __expf(mm - mn) + sl[w] * __expf(sm[w] - mn);
            mm = mn;
        }
        rloss[row] = mm + logf(ll) - lr[targets[row]];
    }
}

__global__ void loss_final_kernel(const float* __restrict__ rloss,
                                  float* __restrict__ out, int out_size) {
    float s = 0.f;
    for (int i = threadIdx.x; i < Mv; i += 256) s += rloss[i];
    #pragma unroll
    for (int off = 32; off; off >>= 1) s += __shfl_xor(s, off, 64);
    __shared__ float sw[4];
    int wave = threadIdx.x >> 6, lane = threadIdx.x & 63;
    if (lane == 0) sw[wave] = s;
    __syncthreads();
    if (threadIdx.x == 0)
        out[out_size - 1] = (sw[0] + sw[1] + sw[2] + sw[3]) / (float)Mv;
}

// ---------------------------------------------------------------------------
extern "C" void kernel_launch(void* const* d_in, const int* in_sizes, int n_in,
                              void* d_out, int out_size, void* d_ws, size_t ws_size,
                              hipStream_t stream) {
    const int*   idx     = (const int*)  d_in[0];
    const int*   targets = (const int*)  d_in[1];
    const float* wte     = (const float*)d_in[2];
    const float* wpe     = (const float*)d_in[3];
    const float* ln1_s   = (const float*)d_in[4];
    const float* ln1_b   = (const float*)d_in[5];
    const float* attn_k  = (const float*)d_in[6];
    const float* attn_b  = (const float*)d_in[7];
    const float* aproj_k = (const float*)d_in[8];
    const float* aproj_b = (const float*)d_in[9];
    const float* ln2_s   = (const float*)d_in[10];
    const float* ln2_b   = (const float*)d_in[11];
    const float* fc_k    = (const float*)d_in[12];
    const float* fc_b    = (const float*)d_in[13];
    const float* mproj_k = (const float*)d_in[14];
    const float* mproj_b = (const float*)d_in[15];
    const float* lnf_s   = (const float*)d_in[16];
    const float* lnf_b   = (const float*)d_in[17];

    float* out = (float*)d_out;
    char* ws = (char*)d_ws;

    // workspace layout (byte offsets); wte_bf aliases the dead mid-loop region
    constexpr size_t NEED = 86712320ULL;
    if (ws_size < NEED) return;
    float*          x      = (float*)(ws + 0);
    float*          rloss  = (float*)(ws + 6291456);
    __hip_bfloat16* h_bf   = (__hip_bfloat16*)(ws + 6299648);
    float*          qkvb   = (float*)(ws + 9445376);
    __hip_bfloat16* att_bf = (__hip_bfloat16*)(ws + 28319744);
    __hip_bfloat16* fco_bf = (__hip_bfloat16*)(ws + 31465472);
    __hip_bfloat16* w0     = (__hip_bfloat16*)(ws + 44048384);  // qkv^T  [2304][768]
    __hip_bfloat16* w1     = (__hip_bfloat16*)(ws + 47587328);  // aproj^T [768][768]
    __hip_bfloat16* w2     = (__hip_bfloat16*)(ws + 48766976);  // fc^T   [3072][768]
    __hip_bfloat16* w3     = (__hip_bfloat16*)(ws + 53485568);  // mproj^T [768][3072]
    __hip_bfloat16* wte_bf = (__hip_bfloat16*)(ws + 9445376);   // [50304][768] aliased

    embed_kernel<<<Mv, 256, 0, stream>>>(idx, wte, wpe, x);

    for (int l = 0; l < Lv; ++l) {
        wtrans_kernel<<<dim3(72, 24), 256, 0, stream>>>(
            attn_k + (size_t)l * Cv * 2304, w0, Cv, 2304);
        wtrans_kernel<<<dim3(24, 24), 256, 0, stream>>>(
            aproj_k + (size_t)l * Cv * Cv, w1, Cv, Cv);
        wtrans_kernel<<<dim3(96, 24), 256, 0, stream>>>(
            fc_k + (size_t)l * Cv * 3072, w2, Cv, 3072);
        wtrans_kernel<<<dim3(24, 96), 256, 0, stream>>>(
            mproj_k + (size_t)l * 3072 * Cv, w3, 3072, Cv);

        ln_kernel<<<Mv, 256, 0, stream>>>(x, ln1_s + l * Cv, ln1_b + l * Cv, h_bf);
        gemm_bf16<0><<<dim3(18, 16), 256, 0, stream>>>(
            h_bf, w0, attn_b + l * 2304, nullptr, qkvb, nullptr, Mv, 2304, Cv);
        attn_kernel<<<dim3(Tv / 16, Bv * Hv), 256, 0, stream>>>(qkvb, att_bf);
        gemm_bf16<1><<<dim3(6, 16), 256, 0, stream>>>(
            att_bf, w1, aproj_b + l * Cv, x, x, nullptr, Mv, Cv, Cv);
        ln_kernel<<<Mv, 256, 0, stream>>>(x, ln2_s + l * Cv, ln2_b + l * Cv, h_bf);
        gemm_bf16<2><<<dim3(24, 16), 256, 0, stream>>>(
            h_bf, w2, fc_b + l * 3072, nullptr, nullptr, fco_bf, Mv, 3072, Cv);
        gemm_bf16<1><<<dim3(6, 16), 256, 0, stream>>>(
            fco_bf, w3, mproj_b + l * Cv, x, x, nullptr, Mv, Cv, 3072);
    }

    ln_kernel<<<Mv, 256, 0, stream>>>(x, lnf_s, lnf_b, h_bf);
    cvt_kernel<<<2048, 256, 0, stream>>>(wte, wte_bf, (Vv * Cv) / 4);
    gemm_bf16<3><<<dim3(393, 16), 256, 0, stream>>>(
        h_bf, wte_bf, nullptr, nullptr, out, nullptr, Mv, Vv, Cv);

    loss_rows_kernel<<<Mv, 256, 0, stream>>>(out, targets, rloss);
    loss_final_kernel<<<1, 256, 0, stream>>>(rloss, out, out_size);
}

// Round 4
// 1855.880 us; speedup vs baseline: 4.8498x; 1.1308x over previous
//
#include <hip/hip_runtime.h>
#include <hip/hip_bf16.h>
#include <math.h>

typedef __attribute__((ext_vector_type(8))) short bf16x8;
typedef __attribute__((ext_vector_type(4))) float f32x4;

static constexpr int Bv   = 2;
static constexpr int Tv   = 1024;
static constexpr int Cv   = 768;
static constexpr int Hv   = 12;
static constexpr int Lv   = 4;
static constexpr int Vv   = 50257;
static constexpr int Mv   = 2048;
static constexpr int NTv  = 393;          // lm-head col tiles of 128
static constexpr float EPSv = 1e-6f;

// ---------------------------------------------------------------------------
__device__ __forceinline__ void gload16(const void* g, void* l) {
    __builtin_amdgcn_global_load_lds((const __attribute__((address_space(1))) void*)g,
                                     (__attribute__((address_space(3))) void*)l, 16, 0, 0);
}

// ---------------------------------------------------------------------------
__global__ void embed_kernel(const int* __restrict__ idx,
                             const float* __restrict__ wte,
                             const float* __restrict__ wpe,
                             float* __restrict__ x) {
    int row = blockIdx.x;
    int t   = row & (Tv - 1);
    int tok = idx[row];
    const float* src = wte + (size_t)tok * Cv;
    const float* pos = wpe + (size_t)t * Cv;
    float* dst = x + (size_t)row * Cv;
    for (int c = threadIdx.x; c < Cv; c += 256)
        dst[c] = src[c] + pos[c];
}

// ---------------------------------------------------------------------------
// LayerNorm, one wave per row. fp32 in -> bf16 out. grid 512 x 256.
// ---------------------------------------------------------------------------
__device__ __forceinline__ ushort4 pack4bf(float4 v) {
    ushort4 u;
    u.x = __bfloat16_as_ushort(__float2bfloat16(v.x));
    u.y = __bfloat16_as_ushort(__float2bfloat16(v.y));
    u.z = __bfloat16_as_ushort(__float2bfloat16(v.z));
    u.w = __bfloat16_as_ushort(__float2bfloat16(v.w));
    return u;
}

__global__ void ln_kernel(const float* __restrict__ in,
                          const float* __restrict__ sc,
                          const float* __restrict__ bi,
                          __hip_bfloat16* __restrict__ out) {
    int row  = blockIdx.x * 4 + (threadIdx.x >> 6);
    int lane = threadIdx.x & 63;
    const float4* xr = (const float4*)(in + (size_t)row * Cv);
    float4 a = xr[lane], b = xr[lane + 64], c = xr[lane + 128];
    float sum = a.x + a.y + a.z + a.w + b.x + b.y + b.z + b.w + c.x + c.y + c.z + c.w;
    float sq  = a.x*a.x + a.y*a.y + a.z*a.z + a.w*a.w
              + b.x*b.x + b.y*b.y + b.z*b.z + b.w*b.w
              + c.x*c.x + c.y*c.y + c.z*c.z + c.w*c.w;
    #pragma unroll
    for (int off = 32; off; off >>= 1) {
        sum += __shfl_xor(sum, off, 64);
        sq  += __shfl_xor(sq,  off, 64);
    }
    float mean = sum * (1.0f / Cv);
    float var  = sq * (1.0f / Cv) - mean * mean;
    float rs   = rsqrtf(var + EPSv);
    const float4* s4 = (const float4*)sc;
    const float4* b4 = (const float4*)bi;
    ushort4* orow = (ushort4*)(out + (size_t)row * Cv);
    #pragma unroll
    for (int i = 0; i < 3; ++i) {
        float4 v = (i == 0) ? a : (i == 1) ? b : c;
        float4 s = s4[lane + 64 * i];
        float4 t = b4[lane + 64 * i];
        float4 o;
        o.x = (v.x - mean) * rs * s.x + t.x;
        o.y = (v.y - mean) * rs * s.y + t.y;
        o.z = (v.z - mean) * rs * s.z + t.z;
        o.w = (v.w - mean) * rs * s.w + t.w;
        orow[lane + 64 * i] = pack4bf(o);
    }
}

// ---------------------------------------------------------------------------
// Weight transpose+convert: in fp32 [K][N] -> out bf16 [N][K]
// ---------------------------------------------------------------------------
__global__ void wtrans_kernel(const float* __restrict__ in,
                              __hip_bfloat16* __restrict__ out, int K, int N) {
    __shared__ float tile[32][33];
    int k0 = blockIdx.y * 32, n0 = blockIdx.x * 32;
    int tx = threadIdx.x & 31, ty = threadIdx.x >> 5;   // 32 x 8
    #pragma unroll
    for (int i = 0; i < 4; ++i)
        tile[ty + i * 8][tx] = in[(size_t)(k0 + ty + i * 8) * N + n0 + tx];
    __syncthreads();
    #pragma unroll
    for (int i = 0; i < 4; ++i)
        out[(size_t)(n0 + ty + i * 8) * K + k0 + tx] =
            __float2bfloat16(tile[tx][ty + i * 8]);
}

// ---------------------------------------------------------------------------
// Loop GEMM: 128x64 tile, BK=32, 4 waves (2x2), wave tile 64x32 (4x2 frags).
//   EPI 0: Cf = acc + bias; EPI 1: Cf = acc + bias + R (in-place residual);
//   EPI 2: Cb = bf16(gelu(acc + bias))
// N % 64 == 0, K % 32 == 0, M % 128 == 0 assumed.
// ---------------------------------------------------------------------------
template<int EPI>
__launch_bounds__(256)
__global__ void gemm_bf16(const __hip_bfloat16* __restrict__ A,
                          const __hip_bfloat16* __restrict__ Bt,
                          const float* __restrict__ bias,
                          const float* R, float* Cf,
                          __hip_bfloat16* __restrict__ Cb,
                          int M, int N, int K) {
    __shared__ __hip_bfloat16 As[128 * 32];
    __shared__ __hip_bfloat16 Bs[64 * 32];
    int tid = threadIdx.x;
    int wave = tid >> 6, lane = tid & 63;
    int wr = wave >> 1, wc = wave & 1;
    int rowBase = blockIdx.y * 128, colBase = blockIdx.x * 64;

    f32x4 acc[4][2] = {};

    int srow  = wave * 16 + (lane >> 2);
    int skcol = (lane & 3) * 8;
    const __hip_bfloat16* Ap  = A  + (size_t)(rowBase + srow) * K + skcol;
    const __hip_bfloat16* Ap2 = Ap + (size_t)64 * K;
    const __hip_bfloat16* Bp  = Bt + (size_t)(colBase + srow) * K + skcol;
    __hip_bfloat16* AsW  = &As[wave * 512];
    __hip_bfloat16* AsW2 = &As[2048 + wave * 512];
    __hip_bfloat16* BsW  = &Bs[wave * 512];

    int aoff = (wr * 64 + (lane & 15)) * 32 + (lane >> 4) * 8;
    int boff = (wc * 32 + (lane & 15)) * 32 + (lane >> 4) * 8;

    for (int k0 = 0; k0 < K; k0 += 32) {
        gload16(Ap,  AsW);
        gload16(Ap2, AsW2);
        gload16(Bp,  BsW);
        Ap += 32; Ap2 += 32; Bp += 32;
        __syncthreads();

        bf16x8 av[4], bv[2];
        #pragma unroll
        for (int m = 0; m < 4; ++m)
            av[m] = *(const bf16x8*)&As[aoff + m * 16 * 32];
        #pragma unroll
        for (int n = 0; n < 2; ++n)
            bv[n] = *(const bf16x8*)&Bs[boff + n * 16 * 32];
        #pragma unroll
        for (int m = 0; m < 4; ++m)
            #pragma unroll
            for (int n = 0; n < 2; ++n)
                acc[m][n] = __builtin_amdgcn_mfma_f32_16x16x32_bf16(
                    av[m], bv[n], acc[m][n], 0, 0, 0);
        __syncthreads();
    }

    int fq = lane >> 4, fr = lane & 15;
    #pragma unroll
    for (int m = 0; m < 4; ++m) {
        #pragma unroll
        for (int n = 0; n < 2; ++n) {
            f32x4 v = acc[m][n];
            int col = colBase + wc * 32 + n * 16 + fr;
            #pragma unroll
            for (int j = 0; j < 4; ++j) {
                int row = rowBase + wr * 64 + m * 16 + fq * 4 + j;
                float val = v[j] + bias[col];
                if (EPI == 1) val += R[(size_t)row * N + col];
                if (EPI == 2) {
                    float u = val;
                    float cc = 0.7978845608028654f * (u + 0.044715f * u * u * u);
                    val = 0.5f * u * (1.0f + tanhf(cc));
                    Cb[(size_t)row * N + col] = __float2bfloat16(val);
                } else {
                    Cf[(size_t)row * N + col] = val;
                }
            }
        }
    }
}

// ---------------------------------------------------------------------------
// lm-head: logits[2048][V] = h_bf[2048][768] @ wte[V][768]^T  (fp32 B, staged
// with in-flight cvt). 128x128 tile, fused per-block partial logsumexp.
// grid: 6288 1D blocks, chunked-XCD swizzle, row-tiles fastest (L2 reuse of B).
// ---------------------------------------------------------------------------
__launch_bounds__(256)
__global__ void lmhead_kernel(const __hip_bfloat16* __restrict__ A,
                              const float* __restrict__ W,
                              float* __restrict__ Cf,
                              float2* __restrict__ pLse) {
    constexpr int K = Cv, N = Vv;
    __shared__ __hip_bfloat16 As[128 * 32];
    __shared__ __hip_bfloat16 Bs[128 * 32];
    __shared__ float pm2[2][128], pl2[2][128];

    int bid = blockIdx.x;
    int nid = (bid & 7) * (NTv * 16 / 8) + (bid >> 3);   // chunked XCD swizzle (6288/8=786)
    int rowT = nid & 15, colT = nid >> 4;
    int rowBase = rowT * 128, colBase = colT * 128;

    int tid = threadIdx.x, wave = tid >> 6, lane = tid & 63;
    int wr = wave >> 1, wc = wave & 1;

    f32x4 acc[4][4] = {};

    int srow  = wave * 16 + (lane >> 2);
    int skcol = (lane & 3) * 8;
    const __hip_bfloat16* Ap  = A + (size_t)(rowBase + srow) * K + skcol;
    const __hip_bfloat16* Ap2 = Ap + (size_t)64 * K;
    int brow1 = colBase + srow;
    int brow2 = brow1 + 64;
    const float* Wp1 = W + (size_t)(brow1 < N ? brow1 : N - 1) * K + skcol;
    const float* Wp2 = W + (size_t)(brow2 < N ? brow2 : N - 1) * K + skcol;
    __hip_bfloat16* AsW  = &As[wave * 512];
    __hip_bfloat16* AsW2 = &As[2048 + wave * 512];
    int bst1 = wave * 512 + (lane & 63) * 8;
    int bst2 = 2048 + bst1;

    int aoff = (wr * 64 + (lane & 15)) * 32 + (lane >> 4) * 8;
    int boff = (wc * 64 + (lane & 15)) * 32 + (lane >> 4) * 8;

    for (int k0 = 0; k0 < K; k0 += 32) {
        gload16(Ap,  AsW);
        gload16(Ap2, AsW2);
        Ap += 32; Ap2 += 32;
        {   // stage fp32 B -> bf16 LDS (reg path)
            float4 u0 = *(const float4*)(Wp1);
            float4 u1 = *(const float4*)(Wp1 + 4);
            float4 u2 = *(const float4*)(Wp2);
            float4 u3 = *(const float4*)(Wp2 + 4);
            Wp1 += 32; Wp2 += 32;
            bf16x8 p0, p1;
            p0[0] = (short)__bfloat16_as_ushort(__float2bfloat16(u0.x));
            p0[1] = (short)__bfloat16_as_ushort(__float2bfloat16(u0.y));
            p0[2] = (short)__bfloat16_as_ushort(__float2bfloat16(u0.z));
            p0[3] = (short)__bfloat16_as_ushort(__float2bfloat16(u0.w));
            p0[4] = (short)__bfloat16_as_ushort(__float2bfloat16(u1.x));
            p0[5] = (short)__bfloat16_as_ushort(__float2bfloat16(u1.y));
            p0[6] = (short)__bfloat16_as_ushort(__float2bfloat16(u1.z));
            p0[7] = (short)__bfloat16_as_ushort(__float2bfloat16(u1.w));
            p1[0] = (short)__bfloat16_as_ushort(__float2bfloat16(u2.x));
            p1[1] = (short)__bfloat16_as_ushort(__float2bfloat16(u2.y));
            p1[2] = (short)__bfloat16_as_ushort(__float2bfloat16(u2.z));
            p1[3] = (short)__bfloat16_as_ushort(__float2bfloat16(u2.w));
            p1[4] = (short)__bfloat16_as_ushort(__float2bfloat16(u3.x));
            p1[5] = (short)__bfloat16_as_ushort(__float2bfloat16(u3.y));
            p1[6] = (short)__bfloat16_as_ushort(__float2bfloat16(u3.z));
            p1[7] = (short)__bfloat16_as_ushort(__float2bfloat16(u3.w));
            *(bf16x8*)&Bs[bst1] = p0;
            *(bf16x8*)&Bs[bst2] = p1;
        }
        __syncthreads();

        bf16x8 av[4], bv[4];
        #pragma unroll
        for (int m = 0; m < 4; ++m)
            av[m] = *(const bf16x8*)&As[aoff + m * 16 * 32];
        #pragma unroll
        for (int n = 0; n < 4; ++n)
            bv[n] = *(const bf16x8*)&Bs[boff + n * 16 * 32];
        #pragma unroll
        for (int m = 0; m < 4; ++m)
            #pragma unroll
            for (int n = 0; n < 4; ++n)
                acc[m][n] = __builtin_amdgcn_mfma_f32_16x16x32_bf16(
                    av[m], bv[n], acc[m][n], 0, 0, 0);
        __syncthreads();
    }

    int fq = lane >> 4, fr = lane & 15;

    // store logits (guarded scalar; 16 fr-lanes give 64B segments)
    #pragma unroll
    for (int m = 0; m < 4; ++m) {
        #pragma unroll
        for (int n = 0; n < 4; ++n) {
            int col = colBase + wc * 64 + n * 16 + fr;
            if (col >= N) continue;
            #pragma unroll
            for (int j = 0; j < 4; ++j) {
                int row = rowBase + wr * 64 + m * 16 + fq * 4 + j;
                Cf[(size_t)row * N + col] = acc[m][n][j];
            }
        }
    }

    // fused partial logsumexp over this block's 128 cols
    #pragma unroll
    for (int m = 0; m < 4; ++m) {
        #pragma unroll
        for (int j = 0; j < 4; ++j) {
            float v[4], mx = -1e30f;
            #pragma unroll
            for (int n = 0; n < 4; ++n) {
                int col = colBase + wc * 64 + n * 16 + fr;
                v[n] = (col < N) ? acc[m][n][j] : -1e30f;
                mx = fmaxf(mx, v[n]);
            }
            #pragma unroll
            for (int off = 8; off; off >>= 1)
                mx = fmaxf(mx, __shfl_xor(mx, off, 64));
            float s = 0.f;
            #pragma unroll
            for (int n = 0; n < 4; ++n) s += __expf(v[n] - mx);
            #pragma unroll
            for (int off = 8; off; off >>= 1)
                s += __shfl_xor(s, off, 64);
            if (fr == 0) {
                int rloc = wr * 64 + m * 16 + fq * 4 + j;
                pm2[wc][rloc] = mx;
                pl2[wc][rloc] = s;
            }
        }
    }
    __syncthreads();
    if (tid < 128) {
        float m0 = pm2[0][tid], l0 = pl2[0][tid];
        float m1 = pm2[1][tid], l1 = pl2[1][tid];
        float mn = fmaxf(m0, m1);
        float l = l0 * __expf(m0 - mn) + l1 * __expf(m1 - mn);
        pLse[(size_t)(rowBase + tid) * NTv + colT] = make_float2(mn, l);
    }
}

// ---------------------------------------------------------------------------
// Reduce 393 partial (m,l) per row -> rloss[row]. One wave per row, grid 512.
// ---------------------------------------------------------------------------
__global__ void plse_reduce_kernel(const float2* __restrict__ pLse,
                                   const float* __restrict__ logits,
                                   const int* __restrict__ targets,
                                   float* __restrict__ rloss) {
    int row  = blockIdx.x * 4 + (threadIdx.x >> 6);
    int lane = threadIdx.x & 63;
    const float2* pr = pLse + (size_t)row * NTv;
    float m = -1e30f, l = 0.f;
    for (int i = lane; i < NTv; i += 64) {
        float2 p = pr[i];
        float mn = fmaxf(m, p.x);
        l = l * __expf(m - mn) + p.y * __expf(p.x - mn);
        m = mn;
    }
    #pragma unroll
    for (int off = 32; off; off >>= 1) {
        float m2 = __shfl_xor(m, off, 64);
        float l2 = __shfl_xor(l, off, 64);
        float mn = fmaxf(m, m2);
        l = l * __expf(m - mn) + l2 * __expf(m2 - mn);
        m = mn;
    }
    if (lane == 0)
        rloss[row] = m + __logf(l) - logits[(size_t)row * Vv + targets[row]];
}

__global__ void loss_final_kernel(const float* __restrict__ rloss,
                                  float* __restrict__ out, int out_size) {
    float s = 0.f;
    for (int i = threadIdx.x; i < Mv; i += 256) s += rloss[i];
    #pragma unroll
    for (int off = 32; off; off >>= 1) s += __shfl_xor(s, off, 64);
    __shared__ float sw[4];
    int wave = threadIdx.x >> 6, lane = threadIdx.x & 63;
    if (lane == 0) sw[wave] = s;
    __syncthreads();
    if (threadIdx.x == 0)
        out[out_size - 1] = (sw[0] + sw[1] + sw[2] + sw[3]) / (float)Mv;
}

// ---------------------------------------------------------------------------
// Tiled causal attention (unchanged from round 3).
// ---------------------------------------------------------------------------
__launch_bounds__(256)
__global__ void attn_kernel(const float* __restrict__ qkv,
                            __hip_bfloat16* __restrict__ att) {
    __shared__ float Kt[64][65];
    __shared__ float Vs[64][68];
    __shared__ float qs[16][64];
    __shared__ float ps[4][4][64];
    int bh = blockIdx.y;
    int b = bh / Hv, h = bh % Hv;
    int q0 = blockIdx.x * 16;
    int wave = threadIdx.x >> 6, lane = threadIdx.x & 63;
    const float* base = qkv + (size_t)b * Tv * 2304 + h * 192;

    {
        int r = threadIdx.x >> 4;
        int d = (threadIdx.x & 15) * 4;
        float4 v = *(const float4*)(base + (size_t)(q0 + r) * 2304 + d);
        *(float4*)&qs[r][d] = v;
    }

    float acc[4]  = {0.f, 0.f, 0.f, 0.f};
    float mrow[4] = {-3.4e38f, -3.4e38f, -3.4e38f, -3.4e38f};
    float lrow[4] = {0.f, 0.f, 0.f, 0.f};
    int qrow = wave * 4;
    int nt = (q0 >> 6) + 1;

    for (int tix = 0; tix < nt; ++tix) {
        int s0 = tix * 64;
        __syncthreads();
        {
            int s  = threadIdx.x >> 2;
            int dg = (threadIdx.x & 3) * 16;
            const float* krow = base + (size_t)(s0 + s) * 2304 + 64;
            #pragma unroll
            for (int i = 0; i < 4; ++i) {
                float4 v = *(const float4*)(krow + dg + i * 4);
                Kt[dg + i * 4 + 0][s] = v.x;
                Kt[dg + i * 4 + 1][s] = v.y;
                Kt[dg + i * 4 + 2][s] = v.z;
                Kt[dg + i * 4 + 3][s] = v.w;
            }
            const float* vrow = krow + 64;
            #pragma unroll
            for (int i = 0; i < 4; ++i)
                *(float4*)&Vs[s][dg + i * 4] = *(const float4*)(vrow + dg + i * 4);
        }
        __syncthreads();

        float sc[4] = {0.f, 0.f, 0.f, 0.f};
        #pragma unroll 4
        for (int d = 0; d < 64; d += 4) {
            float k0v = Kt[d + 0][lane];
            float k1v = Kt[d + 1][lane];
            float k2v = Kt[d + 2][lane];
            float k3v = Kt[d + 3][lane];
            #pragma unroll
            for (int r = 0; r < 4; ++r) {
                float4 q4 = *(const float4*)&qs[qrow + r][d];
                sc[r] += q4.x * k0v + q4.y * k1v + q4.z * k2v + q4.w * k3v;
            }
        }

        float crs[4];
        #pragma unroll
        for (int r = 0; r < 4; ++r) {
            int trow = q0 + qrow + r;
            bool valid = (s0 + lane) <= trow;
            float sv = valid ? sc[r] * 0.125f : -3.4e38f;
            float mx = sv;
            #pragma unroll
            for (int off = 32; off; off >>= 1) mx = fmaxf(mx, __shfl_xor(mx, off, 64));
            float mnew = fmaxf(mrow[r], mx);
            float p = valid ? __expf(sc[r] * 0.125f - mnew) : 0.f;
            float sum = p;
            #pragma unroll
            for (int off = 32; off; off >>= 1) sum += __shfl_xor(sum, off, 64);
            crs[r] = __expf(mrow[r] - mnew);
            lrow[r] = lrow[r] * crs[r] + sum;
            mrow[r] = mnew;
            ps[wave][r][lane] = p;
        }

        #pragma unroll
        for (int r = 0; r < 4; ++r) acc[r] *= crs[r];
        #pragma unroll 4
        for (int j = 0; j < 64; j += 4) {
            float4 p0 = *(const float4*)&ps[wave][0][j];
            float4 p1 = *(const float4*)&ps[wave][1][j];
            float4 p2 = *(const float4*)&ps[wave][2][j];
            float4 p3 = *(const float4*)&ps[wave][3][j];
            float v0 = Vs[j + 0][lane];
            float v1 = Vs[j + 1][lane];
            float v2 = Vs[j + 2][lane];
            float v3 = Vs[j + 3][lane];
            acc[0] += p0.x * v0 + p0.y * v1 + p0.z * v2 + p0.w * v3;
            acc[1] += p1.x * v0 + p1.y * v1 + p1.z * v2 + p1.w * v3;
            acc[2] += p2.x * v0 + p2.y * v1 + p2.z * v2 + p2.w * v3;
            acc[3] += p3.x * v0 + p3.y * v1 + p3.z * v2 + p3.w * v3;
        }
    }

    #pragma unroll
    for (int r = 0; r < 4; ++r)
        att[(size_t)(b * Tv + q0 + qrow + r) * Cv + h * 64 + lane] =
            __float2bfloat16(acc[r] / lrow[r]);
}

// ---------------------------------------------------------------------------
extern "C" void kernel_launch(void* const* d_in, const int* in_sizes, int n_in,
                              void* d_out, int out_size, void* d_ws, size_t ws_size,
                              hipStream_t stream) {
    const int*   idx     = (const int*)  d_in[0];
    const int*   targets = (const int*)  d_in[1];
    const float* wte     = (const float*)d_in[2];
    const float* wpe     = (const float*)d_in[3];
    const float* ln1_s   = (const float*)d_in[4];
    const float* ln1_b   = (const float*)d_in[5];
    const float* attn_k  = (const float*)d_in[6];
    const float* attn_b  = (const float*)d_in[7];
    const float* aproj_k = (const float*)d_in[8];
    const float* aproj_b = (const float*)d_in[9];
    const float* ln2_s   = (const float*)d_in[10];
    const float* ln2_b   = (const float*)d_in[11];
    const float* fc_k    = (const float*)d_in[12];
    const float* fc_b    = (const float*)d_in[13];
    const float* mproj_k = (const float*)d_in[14];
    const float* mproj_b = (const float*)d_in[15];
    const float* lnf_s   = (const float*)d_in[16];
    const float* lnf_b   = (const float*)d_in[17];

    float* out = (float*)d_out;
    char* ws = (char*)d_ws;

    constexpr size_t NEED = 64643072ULL;
    if (ws_size < NEED) return;
    float*          x      = (float*)(ws + 0);
    float*          rloss  = (float*)(ws + 6291456);
    __hip_bfloat16* h_bf   = (__hip_bfloat16*)(ws + 6299648);
    float*          qkvb   = (float*)(ws + 9445376);
    __hip_bfloat16* att_bf = (__hip_bfloat16*)(ws + 28319744);
    __hip_bfloat16* fco_bf = (__hip_bfloat16*)(ws + 31465472);
    __hip_bfloat16* w0     = (__hip_bfloat16*)(ws + 44048384);
    __hip_bfloat16* w1     = (__hip_bfloat16*)(ws + 47587328);
    __hip_bfloat16* w2     = (__hip_bfloat16*)(ws + 48766976);
    __hip_bfloat16* w3     = (__hip_bfloat16*)(ws + 53485568);
    float2*         pLse   = (float2*)(ws + 58204160);

    embed_kernel<<<Mv, 256, 0, stream>>>(idx, wte, wpe, x);

    for (int l = 0; l < Lv; ++l) {
        wtrans_kernel<<<dim3(72, 24), 256, 0, stream>>>(
            attn_k + (size_t)l * Cv * 2304, w0, Cv, 2304);
        wtrans_kernel<<<dim3(24, 24), 256, 0, stream>>>(
            aproj_k + (size_t)l * Cv * Cv, w1, Cv, Cv);
        wtrans_kernel<<<dim3(96, 24), 256, 0, stream>>>(
            fc_k + (size_t)l * Cv * 3072, w2, Cv, 3072);
        wtrans_kernel<<<dim3(24, 96), 256, 0, stream>>>(
            mproj_k + (size_t)l * 3072 * Cv, w3, 3072, Cv);

        ln_kernel<<<512, 256, 0, stream>>>(x, ln1_s + l * Cv, ln1_b + l * Cv, h_bf);
        gemm_bf16<0><<<dim3(36, 16), 256, 0, stream>>>(
            h_bf, w0, attn_b + l * 2304, nullptr, qkvb, nullptr, Mv, 2304, Cv);
        attn_kernel<<<dim3(Tv / 16, Bv * Hv), 256, 0, stream>>>(qkvb, att_bf);
        gemm_bf16<1><<<dim3(12, 16), 256, 0, stream>>>(
            att_bf, w1, aproj_b + l * Cv, x, x, nullptr, Mv, Cv, Cv);
        ln_kernel<<<512, 256, 0, stream>>>(x, ln2_s + l * Cv, ln2_b + l * Cv, h_bf);
        gemm_bf16<2><<<dim3(48, 16), 256, 0, stream>>>(
            h_bf, w2, fc_b + l * 3072, nullptr, nullptr, fco_bf, Mv, 3072, Cv);
        gemm_bf16<1><<<dim3(12, 16), 256, 0, stream>>>(
            fco_bf, w3, mproj_b + l * Cv, x, x, nullptr, Mv, Cv, 3072);
    }

    ln_kernel<<<512, 256, 0, stream>>>(x, lnf_s, lnf_b, h_bf);
    lmhead_kernel<<<16 * NTv, 256, 0, stream>>>(h_bf, wte, out, pLse);
    plse_reduce_kernel<<<512, 256, 0, stream>>>(pLse, out, targets, rloss);
    loss_final_kernel<<<1, 256, 0, stream>>>(rloss, out, out_size);
}

// Round 5
// 1161.513 us; speedup vs baseline: 7.7491x; 1.5978x over previous
//
#include <hip/hip_runtime.h>
#include <hip/hip_bf16.h>
#include <math.h>

typedef __attribute__((ext_vector_type(8))) short bf16x8;
typedef __attribute__((ext_vector_type(4))) float f32x4;

static constexpr int Bv   = 2;
static constexpr int Tv   = 1024;
static constexpr int Cv   = 768;
static constexpr int Hv   = 12;
static constexpr int Lv   = 4;
static constexpr int Vv   = 50257;
static constexpr int Mv   = 2048;
static constexpr int NTv  = 393;          // lm-head col tiles of 128
static constexpr float EPSv = 1e-6f;

// ---------------------------------------------------------------------------
__device__ __forceinline__ void gload16(const void* g, void* l) {
    __builtin_amdgcn_global_load_lds((const __attribute__((address_space(1))) void*)g,
                                     (__attribute__((address_space(3))) void*)l, 16, 0, 0);
}

// ---------------------------------------------------------------------------
__global__ void embed_kernel(const int* __restrict__ idx,
                             const float* __restrict__ wte,
                             const float* __restrict__ wpe,
                             float* __restrict__ x) {
    int row = blockIdx.x;
    int t   = row & (Tv - 1);
    int tok = idx[row];
    const float* src = wte + (size_t)tok * Cv;
    const float* pos = wpe + (size_t)t * Cv;
    float* dst = x + (size_t)row * Cv;
    for (int c = threadIdx.x; c < Cv; c += 256)
        dst[c] = src[c] + pos[c];
}

// ---------------------------------------------------------------------------
__device__ __forceinline__ ushort4 pack4bf(float4 v) {
    ushort4 u;
    u.x = __bfloat16_as_ushort(__float2bfloat16(v.x));
    u.y = __bfloat16_as_ushort(__float2bfloat16(v.y));
    u.z = __bfloat16_as_ushort(__float2bfloat16(v.z));
    u.w = __bfloat16_as_ushort(__float2bfloat16(v.w));
    return u;
}

// LayerNorm, one wave per row. fp32 in -> bf16 out. grid 512 x 256.
__global__ void ln_kernel(const float* __restrict__ in,
                          const float* __restrict__ sc,
                          const float* __restrict__ bi,
                          __hip_bfloat16* __restrict__ out) {
    int row  = blockIdx.x * 4 + (threadIdx.x >> 6);
    int lane = threadIdx.x & 63;
    const float4* xr = (const float4*)(in + (size_t)row * Cv);
    float4 a = xr[lane], b = xr[lane + 64], c = xr[lane + 128];
    float sum = a.x + a.y + a.z + a.w + b.x + b.y + b.z + b.w + c.x + c.y + c.z + c.w;
    float sq  = a.x*a.x + a.y*a.y + a.z*a.z + a.w*a.w
              + b.x*b.x + b.y*b.y + b.z*b.z + b.w*b.w
              + c.x*c.x + c.y*c.y + c.z*c.z + c.w*c.w;
    #pragma unroll
    for (int off = 32; off; off >>= 1) {
        sum += __shfl_xor(sum, off, 64);
        sq  += __shfl_xor(sq,  off, 64);
    }
    float mean = sum * (1.0f / Cv);
    float var  = sq * (1.0f / Cv) - mean * mean;
    float rs   = rsqrtf(var + EPSv);
    const float4* s4 = (const float4*)sc;
    const float4* b4 = (const float4*)bi;
    ushort4* orow = (ushort4*)(out + (size_t)row * Cv);
    #pragma unroll
    for (int i = 0; i < 3; ++i) {
        float4 v = (i == 0) ? a : (i == 1) ? b : c;
        float4 s = s4[lane + 64 * i];
        float4 t = b4[lane + 64 * i];
        float4 o;
        o.x = (v.x - mean) * rs * s.x + t.x;
        o.y = (v.y - mean) * rs * s.y + t.y;
        o.z = (v.z - mean) * rs * s.z + t.z;
        o.w = (v.w - mean) * rs * s.w + t.w;
        orow[lane + 64 * i] = pack4bf(o);
    }
}

// ---------------------------------------------------------------------------
// Weight transpose+convert: in fp32 [K][N] -> out bf16 [N][K]
// ---------------------------------------------------------------------------
__global__ void wtrans_kernel(const float* __restrict__ in,
                              __hip_bfloat16* __restrict__ out, int K, int N) {
    __shared__ float tile[32][33];
    int k0 = blockIdx.y * 32, n0 = blockIdx.x * 32;
    int tx = threadIdx.x & 31, ty = threadIdx.x >> 5;   // 32 x 8
    #pragma unroll
    for (int i = 0; i < 4; ++i)
        tile[ty + i * 8][tx] = in[(size_t)(k0 + ty + i * 8) * N + n0 + tx];
    __syncthreads();
    #pragma unroll
    for (int i = 0; i < 4; ++i)
        out[(size_t)(n0 + ty + i * 8) * K + k0 + tx] =
            __float2bfloat16(tile[tx][ty + i * 8]);
}

// ---------------------------------------------------------------------------
// fp32 -> bf16 convert (wte), float4 granularity, grid-stride.
// ---------------------------------------------------------------------------
__global__ void cvt_kernel(const float* __restrict__ in,
                           __hip_bfloat16* __restrict__ out, int n4) {
    int stride = gridDim.x * 256;
    for (int i = blockIdx.x * 256 + threadIdx.x; i < n4; i += stride) {
        float4 v = ((const float4*)in)[i];
        ((ushort4*)out)[i] = pack4bf(v);
    }
}

// ---------------------------------------------------------------------------
// V transpose per layer: qkv_bf[row][h*192+128+d] -> vt[bh][d][t]  (bf16)
// grid (32 t-tiles, 2 d-tiles, 24 bh), 256 threads.
// ---------------------------------------------------------------------------
__global__ void vtrans_kernel(const __hip_bfloat16* __restrict__ qkv,
                              __hip_bfloat16* __restrict__ vt) {
    __shared__ __hip_bfloat16 tile[32][33];
    int bh = blockIdx.z;
    int b = bh / Hv, h = bh % Hv;
    int t0 = blockIdx.x * 32, d0 = blockIdx.y * 32;
    int tx = threadIdx.x & 31, ty = threadIdx.x >> 5;
    #pragma unroll
    for (int i = 0; i < 4; ++i)
        tile[ty + i * 8][tx] =
            qkv[(size_t)(b * Tv + t0 + ty + i * 8) * 2304 + h * 192 + 128 + d0 + tx];
    __syncthreads();
    #pragma unroll
    for (int i = 0; i < 4; ++i)
        vt[((size_t)bh * 64 + d0 + ty + i * 8) * Tv + t0 + tx] = tile[tx][ty + i * 8];
}

// ---------------------------------------------------------------------------
// Loop GEMM: 128x64 tile, BK=32, 4 waves (2x2), wave tile 64x32 (4x2 frags).
//   EPI 0: Cb = bf16(acc + bias)              (qkv)
//   EPI 1: Cf = acc + bias + R (in-place residual, fp32)
//   EPI 2: Cb = bf16(gelu(acc + bias))
// ---------------------------------------------------------------------------
template<int EPI>
__launch_bounds__(256)
__global__ void gemm_bf16(const __hip_bfloat16* __restrict__ A,
                          const __hip_bfloat16* __restrict__ Bt,
                          const float* __restrict__ bias,
                          const float* R, float* Cf,
                          __hip_bfloat16* __restrict__ Cb,
                          int M, int N, int K) {
    __shared__ __hip_bfloat16 As[128 * 32];
    __shared__ __hip_bfloat16 Bs[64 * 32];
    int tid = threadIdx.x;
    int wave = tid >> 6, lane = tid & 63;
    int wr = wave >> 1, wc = wave & 1;
    int rowBase = blockIdx.y * 128, colBase = blockIdx.x * 64;

    f32x4 acc[4][2] = {};

    int srow  = wave * 16 + (lane >> 2);
    int skcol = (lane & 3) * 8;
    const __hip_bfloat16* Ap  = A  + (size_t)(rowBase + srow) * K + skcol;
    const __hip_bfloat16* Ap2 = Ap + (size_t)64 * K;
    const __hip_bfloat16* Bp  = Bt + (size_t)(colBase + srow) * K + skcol;
    __hip_bfloat16* AsW  = &As[wave * 512];
    __hip_bfloat16* AsW2 = &As[2048 + wave * 512];
    __hip_bfloat16* BsW  = &Bs[wave * 512];

    int aoff = (wr * 64 + (lane & 15)) * 32 + (lane >> 4) * 8;
    int boff = (wc * 32 + (lane & 15)) * 32 + (lane >> 4) * 8;

    for (int k0 = 0; k0 < K; k0 += 32) {
        gload16(Ap,  AsW);
        gload16(Ap2, AsW2);
        gload16(Bp,  BsW);
        Ap += 32; Ap2 += 32; Bp += 32;
        __syncthreads();

        bf16x8 av[4], bv[2];
        #pragma unroll
        for (int m = 0; m < 4; ++m)
            av[m] = *(const bf16x8*)&As[aoff + m * 16 * 32];
        #pragma unroll
        for (int n = 0; n < 2; ++n)
            bv[n] = *(const bf16x8*)&Bs[boff + n * 16 * 32];
        #pragma unroll
        for (int m = 0; m < 4; ++m)
            #pragma unroll
            for (int n = 0; n < 2; ++n)
                acc[m][n] = __builtin_amdgcn_mfma_f32_16x16x32_bf16(
                    av[m], bv[n], acc[m][n], 0, 0, 0);
        __syncthreads();
    }

    int fq = lane >> 4, fr = lane & 15;
    #pragma unroll
    for (int m = 0; m < 4; ++m) {
        #pragma unroll
        for (int n = 0; n < 2; ++n) {
            f32x4 v = acc[m][n];
            int col = colBase + wc * 32 + n * 16 + fr;
            #pragma unroll
            for (int j = 0; j < 4; ++j) {
                int row = rowBase + wr * 64 + m * 16 + fq * 4 + j;
                float val = v[j] + bias[col];
                if (EPI == 1) {
                    val += R[(size_t)row * N + col];
                    Cf[(size_t)row * N + col] = val;
                } else {
                    if (EPI == 2) {
                        float u = val;
                        float cc = 0.7978845608028654f * (u + 0.044715f * u * u * u);
                        val = 0.5f * u * (1.0f + tanhf(cc));
                    }
                    Cb[(size_t)row * N + col] = __float2bfloat16(val);
                }
            }
        }
    }
}

// ---------------------------------------------------------------------------
// MFMA flash attention. grid (24 bh, 16 q-tiles reversed), 256 thr = 4 waves.
// Q-tile 64 rows (16/wave), KV-tile 64. Swizzled LDS (XOR 16B chunk by row&7).
// ---------------------------------------------------------------------------
__launch_bounds__(256)
__global__ void attn_kernel(const __hip_bfloat16* __restrict__ qkv,
                            const __hip_bfloat16* __restrict__ vt,
                            __hip_bfloat16* __restrict__ att) {
    __shared__ __hip_bfloat16 Qs[64 * 64];
    __shared__ __hip_bfloat16 Ks[64 * 64];
    __shared__ __hip_bfloat16 Vs[64 * 64];   // Vs[d][k]
    __shared__ __hip_bfloat16 Ps[64 * 64];
    int bh = blockIdx.x;
    int b = bh / Hv, h = bh % Hv;
    int qt = (int)gridDim.y - 1 - (int)blockIdx.y;   // heavy tiles first
    int q0 = qt * 64;
    int tid = threadIdx.x, wave = tid >> 6, lane = tid & 63;
    int g = lane >> 4, fr = lane & 15;
    int srow8 = lane >> 3, sc8 = lane & 7;

    // stage Q once (swizzled source, linear LDS dest)
    const __hip_bfloat16* qbase = qkv + (size_t)(b * Tv + q0) * 2304 + h * 192;
    #pragma unroll
    for (int i = 0; i < 2; ++i) {
        int row = wave * 16 + i * 8 + srow8;
        gload16(qbase + (size_t)row * 2304 + ((sc8 ^ (row & 7)) * 8),
                Qs + (wave * 16 + i * 8) * 64);
    }

    f32x4 accO[4] = {};
    float mrun[4] = {-1e30f, -1e30f, -1e30f, -1e30f};
    float lrun[4] = {0.f, 0.f, 0.f, 0.f};

    for (int kv = 0; kv <= qt; ++kv) {
        int s0 = kv * 64;
        __syncthreads();    // prev PV done (iter0: nothing)
        const __hip_bfloat16* kbase = qkv + (size_t)(b * Tv + s0) * 2304 + h * 192 + 64;
        const __hip_bfloat16* vbase = vt + (size_t)bh * 64 * Tv + s0;
        #pragma unroll
        for (int i = 0; i < 2; ++i) {
            int row = wave * 16 + i * 8 + srow8;
            gload16(kbase + (size_t)row * 2304 + ((sc8 ^ (row & 7)) * 8),
                    Ks + (wave * 16 + i * 8) * 64);
            gload16(vbase + (size_t)row * Tv + ((sc8 ^ (row & 7)) * 8),
                    Vs + (wave * 16 + i * 8) * 64);
        }
        __syncthreads();    // K/V (and Q on iter0) ready

        // QK^T: S[16q][64key] per wave
        f32x4 s4[4] = {};
        #pragma unroll
        for (int kk = 0; kk < 2; ++kk) {
            int qrow = wave * 16 + fr;
            bf16x8 qa = *(const bf16x8*)&Qs[qrow * 64 + (((g + 4 * kk) ^ (fr & 7)) * 8)];
            #pragma unroll
            for (int n = 0; n < 4; ++n) {
                int krow = n * 16 + fr;
                bf16x8 kb = *(const bf16x8*)&Ks[krow * 64 + (((g + 4 * kk) ^ (fr & 7)) * 8)];
                s4[n] = __builtin_amdgcn_mfma_f32_16x16x32_bf16(qa, kb, s4[n], 0, 0, 0);
            }
        }

        // online softmax (rows q = wave*16 + g*4 + j; keys 16n + fr)
        bool dia = (kv == qt);
        #pragma unroll
        for (int j = 0; j < 4; ++j) {
            int qg = q0 + wave * 16 + g * 4 + j;
            float sj[4], mx = -1e30f;
            #pragma unroll
            for (int n = 0; n < 4; ++n) {
                float v = s4[n][j] * 0.125f;
                if (dia && (s0 + n * 16 + fr) > qg) v = -1e30f;
                sj[n] = v;
                mx = fmaxf(mx, v);
            }
            #pragma unroll
            for (int off = 1; off < 16; off <<= 1)
                mx = fmaxf(mx, __shfl_xor(mx, off, 64));
            float mnew = fmaxf(mrun[j], mx);
            float ps = 0.f;
            unsigned short pb[4];
            #pragma unroll
            for (int n = 0; n < 4; ++n) {
                float p = __expf(sj[n] - mnew);
                __hip_bfloat16 pc = __float2bfloat16(p);
                pb[n] = __bfloat16_as_ushort(pc);
                ps += __bfloat162float(pc);     // keep l consistent with stored P
            }
            #pragma unroll
            for (int off = 1; off < 16; off <<= 1)
                ps += __shfl_xor(ps, off, 64);
            float cr = __expf(mrun[j] - mnew);
            lrun[j] = lrun[j] * cr + ps;
            mrun[j] = mnew;
            int prow = wave * 16 + g * 4 + j;
            #pragma unroll
            for (int n = 0; n < 4; ++n) {
                int byteoff = (32 * n + 2 * fr) ^ ((prow & 7) << 4);
                ((unsigned short*)Ps)[prow * 64 + (byteoff >> 1)] = pb[n];
            }
            #pragma unroll
            for (int n = 0; n < 4; ++n) accO[n][j] *= cr;
        }
        __syncthreads();    // P ready, all QK reads of Ks done

        // PV: O[16q][64d] += P[16q][64k] * V[64k][64d]
        #pragma unroll
        for (int kk = 0; kk < 2; ++kk) {
            int prow = wave * 16 + fr;
            bf16x8 pa = *(const bf16x8*)&Ps[prow * 64 + (((g + 4 * kk) ^ (fr & 7)) * 8)];
            #pragma unroll
            for (int n = 0; n < 4; ++n) {
                int vrow = n * 16 + fr;       // d-column
                bf16x8 vb = *(const bf16x8*)&Vs[vrow * 64 + (((g + 4 * kk) ^ (fr & 7)) * 8)];
                accO[n] = __builtin_amdgcn_mfma_f32_16x16x32_bf16(pa, vb, accO[n], 0, 0, 0);
            }
        }
    }

    #pragma unroll
    for (int j = 0; j < 4; ++j) {
        float inv = 1.0f / lrun[j];
        int row = b * Tv + q0 + wave * 16 + g * 4 + j;
        #pragma unroll
        for (int n = 0; n < 4; ++n)
            att[(size_t)row * Cv + h * 64 + n * 16 + fr] =
                __float2bfloat16(accO[n][j] * inv);
    }
}

// ---------------------------------------------------------------------------
// lm-head: logits = h_bf @ wte_bf^T, bf16 MFMA, gload_lds both operands,
// fused per-block exp-sum (logits are small, no max shift needed).
// grid 6288 1D, chunked XCD swizzle, row-tiles fastest.
// ---------------------------------------------------------------------------
__launch_bounds__(256)
__global__ void lmhead_kernel(const __hip_bfloat16* __restrict__ A,
                              const __hip_bfloat16* __restrict__ Bt,
                              float* __restrict__ Cf,
                              float* __restrict__ pLse) {
    constexpr int K = Cv, N = Vv;
    __shared__ __hip_bfloat16 As[128 * 32];
    __shared__ __hip_bfloat16 Bs[128 * 32];
    __shared__ float ps2[2][128];

    int bid = blockIdx.x;
    int nid = (bid & 7) * (NTv * 16 / 8) + (bid >> 3);
    int rowT = nid & 15, colT = nid >> 4;
    int rowBase = rowT * 128, colBase = colT * 128;

    int tid = threadIdx.x, wave = tid >> 6, lane = tid & 63;
    int wr = wave >> 1, wc = wave & 1;

    f32x4 acc[4][4] = {};

    int srow  = wave * 16 + (lane >> 2);
    int skcol = (lane & 3) * 8;
    const __hip_bfloat16* Ap  = A + (size_t)(rowBase + srow) * K + skcol;
    const __hip_bfloat16* Ap2 = Ap + (size_t)64 * K;
    int brow1 = colBase + srow;           // always < N (50176+63 max in-range)
    int brow2 = brow1 + 64;
    const __hip_bfloat16* Bp  = Bt + (size_t)brow1 * K + skcol;
    const __hip_bfloat16* Bp2 = Bt + (size_t)(brow2 < N ? brow2 : N - 1) * K + skcol;
    __hip_bfloat16* AsW  = &As[wave * 512];
    __hip_bfloat16* AsW2 = &As[2048 + wave * 512];
    __hip_bfloat16* BsW  = &Bs[wave * 512];
    __hip_bfloat16* BsW2 = &Bs[2048 + wave * 512];

    int aoff = (wr * 64 + (lane & 15)) * 32 + (lane >> 4) * 8;
    int boff = (wc * 64 + (lane & 15)) * 32 + (lane >> 4) * 8;

    for (int k0 = 0; k0 < K; k0 += 32) {
        gload16(Ap,  AsW);
        gload16(Ap2, AsW2);
        gload16(Bp,  BsW);
        gload16(Bp2, BsW2);
        Ap += 32; Ap2 += 32; Bp += 32; Bp2 += 32;
        __syncthreads();

        bf16x8 av[4], bv[4];
        #pragma unroll
        for (int m = 0; m < 4; ++m)
            av[m] = *(const bf16x8*)&As[aoff + m * 16 * 32];
        #pragma unroll
        for (int n = 0; n < 4; ++n)
            bv[n] = *(const bf16x8*)&Bs[boff + n * 16 * 32];
        #pragma unroll
        for (int m = 0; m < 4; ++m)
            #pragma unroll
            for (int n = 0; n < 4; ++n)
                acc[m][n] = __builtin_amdgcn_mfma_f32_16x16x32_bf16(
                    av[m], bv[n], acc[m][n], 0, 0, 0);
        __syncthreads();
    }

    int fq = lane >> 4, fr = lane & 15;

    // store logits + per-row partial exp-sum over this block's 128 cols
    #pragma unroll
    for (int m = 0; m < 4; ++m) {
        #pragma unroll
        for (int j = 0; j < 4; ++j) {
            int row = rowBase + wr * 64 + m * 16 + fq * 4 + j;
            float s = 0.f;
            #pragma unroll
            for (int n = 0; n < 4; ++n) {
                int col = colBase + wc * 64 + n * 16 + fr;
                float v = acc[m][n][j];
                if (col < N) {
                    Cf[(size_t)row * N + col] = v;
                    s += __expf(v);
                }
            }
            #pragma unroll
            for (int off = 1; off < 16; off <<= 1)
                s += __shfl_xor(s, off, 64);
            if (fr == 0)
                ps2[wc][wr * 64 + m * 16 + fq * 4 + j] = s;
        }
    }
    __syncthreads();
    if (tid < 128)
        pLse[(size_t)(rowBase + tid) * NTv + colT] = ps2[0][tid] + ps2[1][tid];
}

// ---------------------------------------------------------------------------
// Reduce 393 partial sums per row -> rloss. One wave per row, grid 512.
// ---------------------------------------------------------------------------
__global__ void plse_reduce_kernel(const float* __restrict__ pLse,
                                   const float* __restrict__ logits,
                                   const int* __restrict__ targets,
                                   float* __restrict__ rloss) {
    int row  = blockIdx.x * 4 + (threadIdx.x >> 6);
    int lane = threadIdx.x & 63;
    const float* pr = pLse + (size_t)row * NTv;
    float l = 0.f;
    for (int i = lane; i < NTv; i += 64) l += pr[i];
    #pragma unroll
    for (int off = 32; off; off >>= 1) l += __shfl_xor(l, off, 64);
    if (lane == 0)
        rloss[row] = logf(l) - logits[(size_t)row * Vv + targets[row]];
}

__global__ void loss_final_kernel(const float* __restrict__ rloss,
                                  float* __restrict__ out, int out_size) {
    float s = 0.f;
    for (int i = threadIdx.x; i < Mv; i += 256) s += rloss[i];
    #pragma unroll
    for (int off = 32; off; off >>= 1) s += __shfl_xor(s, off, 64);
    __shared__ float sw[4];
    int wave = threadIdx.x >> 6, lane = threadIdx.x & 63;
    if (lane == 0) sw[wave] = s;
    __syncthreads();
    if (threadIdx.x == 0)
        out[out_size - 1] = (sw[0] + sw[1] + sw[2] + sw[3]) / (float)Mv;
}

// ---------------------------------------------------------------------------
extern "C" void kernel_launch(void* const* d_in, const int* in_sizes, int n_in,
                              void* d_out, int out_size, void* d_ws, size_t ws_size,
                              hipStream_t stream) {
    const int*   idx     = (const int*)  d_in[0];
    const int*   targets = (const int*)  d_in[1];
    const float* wte     = (const float*)d_in[2];
    const float* wpe     = (const float*)d_in[3];
    const float* ln1_s   = (const float*)d_in[4];
    const float* ln1_b   = (const float*)d_in[5];
    const float* attn_k  = (const float*)d_in[6];
    const float* attn_b  = (const float*)d_in[7];
    const float* aproj_k = (const float*)d_in[8];
    const float* aproj_b = (const float*)d_in[9];
    const float* ln2_s   = (const float*)d_in[10];
    const float* ln2_b   = (const float*)d_in[11];
    const float* fc_k    = (const float*)d_in[12];
    const float* fc_b    = (const float*)d_in[13];
    const float* mproj_k = (const float*)d_in[14];
    const float* mproj_b = (const float*)d_in[15];
    const float* lnf_s   = (const float*)d_in[16];
    const float* lnf_b   = (const float*)d_in[17];

    float* out = (float*)d_out;
    char* ws  = (char*)d_ws;
    char* ob  = (char*)d_out;   // d_out doubles as loop-time scratch (dead
                                // until lmhead overwrites every logit)

    constexpr size_t NEED = 83568128ULL;
    if (ws_size < NEED) return;

    // ws: live through lm-head
    __hip_bfloat16* wte_bf = (__hip_bfloat16*)(ws + 0);          // 77,194,752
    __hip_bfloat16* h_bf   = (__hip_bfloat16*)(ws + 77194752);   //  3,145,728
    float*          pLse   = (float*)(ws + 80340480);            //  3,219,456
    float*          rloss  = (float*)(ws + 83559936);            //      8,192

    // d_out scratch: all dead before lmhead writes logits
    float*          x      = (float*)(ob + 0);                   //  6,291,456
    __hip_bfloat16* qkv_bf = (__hip_bfloat16*)(ob + 6291456);    //  9,437,184
    __hip_bfloat16* vt_bf  = (__hip_bfloat16*)(ob + 15728640);   //  3,145,728
    __hip_bfloat16* att_bf = (__hip_bfloat16*)(ob + 18874368);   //  3,145,728
    __hip_bfloat16* fco_bf = (__hip_bfloat16*)(ob + 22020096);   // 12,582,912
    __hip_bfloat16* w0     = (__hip_bfloat16*)(ob + 34603008);   //  3,538,944
    __hip_bfloat16* w1     = (__hip_bfloat16*)(ob + 38141952);   //  1,179,648
    __hip_bfloat16* w2     = (__hip_bfloat16*)(ob + 39321600);   //  4,718,592
    __hip_bfloat16* w3     = (__hip_bfloat16*)(ob + 44040192);   //  4,718,592

    embed_kernel<<<Mv, 256, 0, stream>>>(idx, wte, wpe, x);

    for (int l = 0; l < Lv; ++l) {
        wtrans_kernel<<<dim3(72, 24), 256, 0, stream>>>(
            attn_k + (size_t)l * Cv * 2304, w0, Cv, 2304);
        wtrans_kernel<<<dim3(24, 24), 256, 0, stream>>>(
            aproj_k + (size_t)l * Cv * Cv, w1, Cv, Cv);
        wtrans_kernel<<<dim3(96, 24), 256, 0, stream>>>(
            fc_k + (size_t)l * Cv * 3072, w2, Cv, 3072);
        wtrans_kernel<<<dim3(24, 96), 256, 0, stream>>>(
            mproj_k + (size_t)l * 3072 * Cv, w3, 3072, Cv);

        ln_kernel<<<512, 256, 0, stream>>>(x, ln1_s + l * Cv, ln1_b + l * Cv, h_bf);
        gemm_bf16<0><<<dim3(36, 16), 256, 0, stream>>>(
            h_bf, w0, attn_b + l * 2304, nullptr, nullptr, qkv_bf, Mv, 2304, Cv);
        vtrans_kernel<<<dim3(32, 2, 24), 256, 0, stream>>>(qkv_bf, vt_bf);
        attn_kernel<<<dim3(24, 16), 256, 0, stream>>>(qkv_bf, vt_bf, att_bf);
        gemm_bf16<1><<<dim3(12, 16), 256, 0, stream>>>(
            att_bf, w1, aproj_b + l * Cv, x, x, nullptr, Mv, Cv, Cv);
        ln_kernel<<<512, 256, 0, stream>>>(x, ln2_s + l * Cv, ln2_b + l * Cv, h_bf);
        gemm_bf16<2><<<dim3(48, 16), 256, 0, stream>>>(
            h_bf, w2, fc_b + l * 3072, nullptr, nullptr, fco_bf, Mv, 3072, Cv);
        gemm_bf16<1><<<dim3(12, 16), 256, 0, stream>>>(
            fco_bf, w3, mproj_b + l * Cv, x, x, nullptr, Mv, Cv, 3072);
    }

    ln_kernel<<<512, 256, 0, stream>>>(x, lnf_s, lnf_b, h_bf);
    cvt_kernel<<<2048, 256, 0, stream>>>(wte, wte_bf, (Vv * Cv) / 4);
    lmhead_kernel<<<16 * NTv, 256, 0, stream>>>(h_bf, wte_bf, out, pLse);
    plse_reduce_kernel<<<512, 256, 0, stream>>>(pLse, out, targets, rloss);
    loss_final_kernel<<<1, 256, 0, stream>>>(rloss, out, out_size);
}

// Round 6
// 1063.080 us; speedup vs baseline: 8.4666x; 1.0926x over previous
//
#include <hip/hip_runtime.h>
#include <hip/hip_bf16.h>
#include <math.h>

typedef __attribute__((ext_vector_type(8))) short bf16x8;
typedef __attribute__((ext_vector_type(4))) float f32x4;

static constexpr int Bv   = 2;
static constexpr int Tv   = 1024;
static constexpr int Cv   = 768;
static constexpr int Hv   = 12;
static constexpr int Lv   = 4;
static constexpr int Vv   = 50257;
static constexpr int Mv   = 2048;
static constexpr int NTv  = 393;          // lm-head col tiles of 128
static constexpr float EPSv = 1e-6f;

// ---------------------------------------------------------------------------
__device__ __forceinline__ void gload16(const void* g, void* l) {
    __builtin_amdgcn_global_load_lds((const __attribute__((address_space(1))) void*)g,
                                     (__attribute__((address_space(3))) void*)l, 16, 0, 0);
}
__device__ __forceinline__ void waitvm0_barrier() {
    asm volatile("s_waitcnt vmcnt(0)" ::: "memory");
    __builtin_amdgcn_s_barrier();
}

// ---------------------------------------------------------------------------
__global__ void embed_kernel(const int* __restrict__ idx,
                             const float* __restrict__ wte,
                             const float* __restrict__ wpe,
                             float* __restrict__ x) {
    int row = blockIdx.x;
    int t   = row & (Tv - 1);
    int tok = idx[row];
    const float* src = wte + (size_t)tok * Cv;
    const float* pos = wpe + (size_t)t * Cv;
    float* dst = x + (size_t)row * Cv;
    for (int c = threadIdx.x; c < Cv; c += 256)
        dst[c] = src[c] + pos[c];
}

// ---------------------------------------------------------------------------
__device__ __forceinline__ ushort4 pack4bf(float4 v) {
    ushort4 u;
    u.x = __bfloat16_as_ushort(__float2bfloat16(v.x));
    u.y = __bfloat16_as_ushort(__float2bfloat16(v.y));
    u.z = __bfloat16_as_ushort(__float2bfloat16(v.z));
    u.w = __bfloat16_as_ushort(__float2bfloat16(v.w));
    return u;
}

// LayerNorm, one wave per row. fp32 in -> bf16 out. grid 512 x 256.
__global__ void ln_kernel(const float* __restrict__ in,
                          const float* __restrict__ sc,
                          const float* __restrict__ bi,
                          __hip_bfloat16* __restrict__ out) {
    int row  = blockIdx.x * 4 + (threadIdx.x >> 6);
    int lane = threadIdx.x & 63;
    const float4* xr = (const float4*)(in + (size_t)row * Cv);
    float4 a = xr[lane], b = xr[lane + 64], c = xr[lane + 128];
    float sum = a.x + a.y + a.z + a.w + b.x + b.y + b.z + b.w + c.x + c.y + c.z + c.w;
    float sq  = a.x*a.x + a.y*a.y + a.z*a.z + a.w*a.w
              + b.x*b.x + b.y*b.y + b.z*b.z + b.w*b.w
              + c.x*c.x + c.y*c.y + c.z*c.z + c.w*c.w;
    #pragma unroll
    for (int off = 32; off; off >>= 1) {
        sum += __shfl_xor(sum, off, 64);
        sq  += __shfl_xor(sq,  off, 64);
    }
    float mean = sum * (1.0f / Cv);
    float var  = sq * (1.0f / Cv) - mean * mean;
    float rs   = rsqrtf(var + EPSv);
    const float4* s4 = (const float4*)sc;
    const float4* b4 = (const float4*)bi;
    ushort4* orow = (ushort4*)(out + (size_t)row * Cv);
    #pragma unroll
    for (int i = 0; i < 3; ++i) {
        float4 v = (i == 0) ? a : (i == 1) ? b : c;
        float4 s = s4[lane + 64 * i];
        float4 t = b4[lane + 64 * i];
        float4 o;
        o.x = (v.x - mean) * rs * s.x + t.x;
        o.y = (v.y - mean) * rs * s.y + t.y;
        o.z = (v.z - mean) * rs * s.z + t.z;
        o.w = (v.w - mean) * rs * s.w + t.w;
        orow[lane + 64 * i] = pack4bf(o);
    }
}

// ---------------------------------------------------------------------------
// Weight transpose+convert: in fp32 [K][N] -> out bf16 [N][K]
// ---------------------------------------------------------------------------
__global__ void wtrans_kernel(const float* __restrict__ in,
                              __hip_bfloat16* __restrict__ out, int K, int N) {
    __shared__ float tile[32][33];
    int k0 = blockIdx.y * 32, n0 = blockIdx.x * 32;
    int tx = threadIdx.x & 31, ty = threadIdx.x >> 5;   // 32 x 8
    #pragma unroll
    for (int i = 0; i < 4; ++i)
        tile[ty + i * 8][tx] = in[(size_t)(k0 + ty + i * 8) * N + n0 + tx];
    __syncthreads();
    #pragma unroll
    for (int i = 0; i < 4; ++i)
        out[(size_t)(n0 + ty + i * 8) * K + k0 + tx] =
            __float2bfloat16(tile[tx][ty + i * 8]);
}

// ---------------------------------------------------------------------------
// fp32 -> bf16 convert (wte), float4 granularity, grid-stride.
// ---------------------------------------------------------------------------
__global__ void cvt_kernel(const float* __restrict__ in,
                           __hip_bfloat16* __restrict__ out, int n4) {
    int stride = gridDim.x * 256;
    for (int i = blockIdx.x * 256 + threadIdx.x; i < n4; i += stride) {
        float4 v = ((const float4*)in)[i];
        ((ushort4*)out)[i] = pack4bf(v);
    }
}

// ---------------------------------------------------------------------------
// V transpose per layer: qkv_bf[row][h*192+128+d] -> vt[bh][d][t]  (bf16)
// ---------------------------------------------------------------------------
__global__ void vtrans_kernel(const __hip_bfloat16* __restrict__ qkv,
                              __hip_bfloat16* __restrict__ vt) {
    __shared__ __hip_bfloat16 tile[32][33];
    int bh = blockIdx.z;
    int b = bh / Hv, h = bh % Hv;
    int t0 = blockIdx.x * 32, d0 = blockIdx.y * 32;
    int tx = threadIdx.x & 31, ty = threadIdx.x >> 5;
    #pragma unroll
    for (int i = 0; i < 4; ++i)
        tile[ty + i * 8][tx] =
            qkv[(size_t)(b * Tv + t0 + ty + i * 8) * 2304 + h * 192 + 128 + d0 + tx];
    __syncthreads();
    #pragma unroll
    for (int i = 0; i < 4; ++i)
        vt[((size_t)bh * 64 + d0 + ty + i * 8) * Tv + t0 + tx] = tile[tx][ty + i * 8];
}

// ---------------------------------------------------------------------------
// Loop GEMM, 2-phase double-buffered: C[M,N] = A @ Bt^T + epilogue.
// BM x 64 tile, BK=32, 4 waves (2x2); wave tile (BM/2) x 32.
//   EPI 0: Cb = bf16(acc + bias); EPI 1: Cf = acc + bias + R (in-place);
//   EPI 2: Cb = bf16(gelu(acc + bias))
// ---------------------------------------------------------------------------
template<int EPI, int BM>
__launch_bounds__(256)
__global__ void gemm_bf16(const __hip_bfloat16* __restrict__ A,
                          const __hip_bfloat16* __restrict__ Bt,
                          const float* __restrict__ bias,
                          const float* R, float* Cf,
                          __hip_bfloat16* __restrict__ Cb,
                          int M, int N, int K) {
    constexpr int FM = BM / 32;           // A frags per wave
    constexpr int NA = BM / 64;           // 64-row A stage chunks
    __shared__ __hip_bfloat16 As[2][BM * 32];
    __shared__ __hip_bfloat16 Bs[2][64 * 32];
    int tid = threadIdx.x;
    int wave = tid >> 6, lane = tid & 63;
    int wr = wave >> 1, wc = wave & 1;
    int rowBase = blockIdx.y * BM, colBase = blockIdx.x * 64;

    f32x4 acc[FM][2] = {};

    int srow  = wave * 16 + (lane >> 2);
    int skcol = (lane & 3) * 8;
    const __hip_bfloat16* Ap0 = A + (size_t)(rowBase + srow) * K + skcol;
    const __hip_bfloat16* Ap1 = (NA > 1) ? (Ap0 + (size_t)64 * K) : Ap0;
    const __hip_bfloat16* Bp0 = Bt + (size_t)(colBase + srow) * K + skcol;
    int ldso = wave * 512;

    int aoff = (wr * (BM / 2) + (lane & 15)) * 32 + (lane >> 4) * 8;
    int boff = (wc * 32 + (lane & 15)) * 32 + (lane >> 4) * 8;

    // prologue: stage tile 0 -> buf 0
    gload16(Ap0, &As[0][ldso]);
    if constexpr (NA > 1) gload16(Ap1, &As[0][2048 + ldso]);
    gload16(Bp0, &Bs[0][ldso]);
    Ap0 += 32; Ap1 += 32; Bp0 += 32;
    waitvm0_barrier();

    int nt = K / 32;
    for (int t = 0; t < nt - 1; ++t) {
        int cur = t & 1, nxt = cur ^ 1;
        gload16(Ap0, &As[nxt][ldso]);
        if constexpr (NA > 1) gload16(Ap1, &As[nxt][2048 + ldso]);
        gload16(Bp0, &Bs[nxt][ldso]);
        Ap0 += 32; Ap1 += 32; Bp0 += 32;

        bf16x8 av[FM], bv[2];
        #pragma unroll
        for (int m = 0; m < FM; ++m) av[m] = *(const bf16x8*)&As[cur][aoff + m * 512];
        #pragma unroll
        for (int n = 0; n < 2; ++n)  bv[n] = *(const bf16x8*)&Bs[cur][boff + n * 512];
        #pragma unroll
        for (int m = 0; m < FM; ++m)
            #pragma unroll
            for (int n = 0; n < 2; ++n)
                acc[m][n] = __builtin_amdgcn_mfma_f32_16x16x32_bf16(
                    av[m], bv[n], acc[m][n], 0, 0, 0);
        waitvm0_barrier();
    }
    {   // last tile
        int cur = (nt - 1) & 1;
        bf16x8 av[FM], bv[2];
        #pragma unroll
        for (int m = 0; m < FM; ++m) av[m] = *(const bf16x8*)&As[cur][aoff + m * 512];
        #pragma unroll
        for (int n = 0; n < 2; ++n)  bv[n] = *(const bf16x8*)&Bs[cur][boff + n * 512];
        #pragma unroll
        for (int m = 0; m < FM; ++m)
            #pragma unroll
            for (int n = 0; n < 2; ++n)
                acc[m][n] = __builtin_amdgcn_mfma_f32_16x16x32_bf16(
                    av[m], bv[n], acc[m][n], 0, 0, 0);
    }

    int fq = lane >> 4, fr = lane & 15;
    #pragma unroll
    for (int m = 0; m < FM; ++m) {
        #pragma unroll
        for (int n = 0; n < 2; ++n) {
            f32x4 v = acc[m][n];
            int col = colBase + wc * 32 + n * 16 + fr;
            #pragma unroll
            for (int j = 0; j < 4; ++j) {
                int row = rowBase + wr * (BM / 2) + m * 16 + fq * 4 + j;
                float val = v[j] + bias[col];
                if (EPI == 1) {
                    val += R[(size_t)row * N + col];
                    Cf[(size_t)row * N + col] = val;
                } else {
                    if (EPI == 2) {
                        float u = val;
                        float cc = 0.7978845608028654f * (u + 0.044715f * u * u * u);
                        val = 0.5f * u * (1.0f + tanhf(cc));
                    }
                    Cb[(size_t)row * N + col] = __float2bfloat16(val);
                }
            }
        }
    }
}

// ---------------------------------------------------------------------------
// MFMA flash attention (unchanged from round 5).
// ---------------------------------------------------------------------------
__launch_bounds__(256)
__global__ void attn_kernel(const __hip_bfloat16* __restrict__ qkv,
                            const __hip_bfloat16* __restrict__ vt,
                            __hip_bfloat16* __restrict__ att) {
    __shared__ __hip_bfloat16 Qs[64 * 64];
    __shared__ __hip_bfloat16 Ks[64 * 64];
    __shared__ __hip_bfloat16 Vs[64 * 64];   // Vs[d][k]
    __shared__ __hip_bfloat16 Ps[64 * 64];
    int bh = blockIdx.x;
    int b = bh / Hv, h = bh % Hv;
    int qt = (int)gridDim.y - 1 - (int)blockIdx.y;
    int q0 = qt * 64;
    int tid = threadIdx.x, wave = tid >> 6, lane = tid & 63;
    int g = lane >> 4, fr = lane & 15;
    int srow8 = lane >> 3, sc8 = lane & 7;

    const __hip_bfloat16* qbase = qkv + (size_t)(b * Tv + q0) * 2304 + h * 192;
    #pragma unroll
    for (int i = 0; i < 2; ++i) {
        int row = wave * 16 + i * 8 + srow8;
        gload16(qbase + (size_t)row * 2304 + ((sc8 ^ (row & 7)) * 8),
                Qs + (wave * 16 + i * 8) * 64);
    }

    f32x4 accO[4] = {};
    float mrun[4] = {-1e30f, -1e30f, -1e30f, -1e30f};
    float lrun[4] = {0.f, 0.f, 0.f, 0.f};

    for (int kv = 0; kv <= qt; ++kv) {
        int s0 = kv * 64;
        __syncthreads();
        const __hip_bfloat16* kbase = qkv + (size_t)(b * Tv + s0) * 2304 + h * 192 + 64;
        const __hip_bfloat16* vbase = vt + (size_t)bh * 64 * Tv + s0;
        #pragma unroll
        for (int i = 0; i < 2; ++i) {
            int row = wave * 16 + i * 8 + srow8;
            gload16(kbase + (size_t)row * 2304 + ((sc8 ^ (row & 7)) * 8),
                    Ks + (wave * 16 + i * 8) * 64);
            gload16(vbase + (size_t)row * Tv + ((sc8 ^ (row & 7)) * 8),
                    Vs + (wave * 16 + i * 8) * 64);
        }
        __syncthreads();

        f32x4 s4[4] = {};
        #pragma unroll
        for (int kk = 0; kk < 2; ++kk) {
            int qrow = wave * 16 + fr;
            bf16x8 qa = *(const bf16x8*)&Qs[qrow * 64 + (((g + 4 * kk) ^ (fr & 7)) * 8)];
            #pragma unroll
            for (int n = 0; n < 4; ++n) {
                int krow = n * 16 + fr;
                bf16x8 kb = *(const bf16x8*)&Ks[krow * 64 + (((g + 4 * kk) ^ (fr & 7)) * 8)];
                s4[n] = __builtin_amdgcn_mfma_f32_16x16x32_bf16(qa, kb, s4[n], 0, 0, 0);
            }
        }

        bool dia = (kv == qt);
        #pragma unroll
        for (int j = 0; j < 4; ++j) {
            int qg = q0 + wave * 16 + g * 4 + j;
            float sj[4], mx = -1e30f;
            #pragma unroll
            for (int n = 0; n < 4; ++n) {
                float v = s4[n][j] * 0.125f;
                if (dia && (s0 + n * 16 + fr) > qg) v = -1e30f;
                sj[n] = v;
                mx = fmaxf(mx, v);
            }
            #pragma unroll
            for (int off = 1; off < 16; off <<= 1)
                mx = fmaxf(mx, __shfl_xor(mx, off, 64));
            float mnew = fmaxf(mrun[j], mx);
            float ps = 0.f;
            unsigned short pb[4];
            #pragma unroll
            for (int n = 0; n < 4; ++n) {
                float p = __expf(sj[n] - mnew);
                __hip_bfloat16 pc = __float2bfloat16(p);
                pb[n] = __bfloat16_as_ushort(pc);
                ps += __bfloat162float(pc);
            }
            #pragma unroll
            for (int off = 1; off < 16; off <<= 1)
                ps += __shfl_xor(ps, off, 64);
            float cr = __expf(mrun[j] - mnew);
            lrun[j] = lrun[j] * cr + ps;
            mrun[j] = mnew;
            int prow = wave * 16 + g * 4 + j;
            #pragma unroll
            for (int n = 0; n < 4; ++n) {
                int byteoff = (32 * n + 2 * fr) ^ ((prow & 7) << 4);
                ((unsigned short*)Ps)[prow * 64 + (byteoff >> 1)] = pb[n];
            }
            #pragma unroll
            for (int n = 0; n < 4; ++n) accO[n][j] *= cr;
        }
        __syncthreads();

        #pragma unroll
        for (int kk = 0; kk < 2; ++kk) {
            int prow = wave * 16 + fr;
            bf16x8 pa = *(const bf16x8*)&Ps[prow * 64 + (((g + 4 * kk) ^ (fr & 7)) * 8)];
            #pragma unroll
            for (int n = 0; n < 4; ++n) {
                int vrow = n * 16 + fr;
                bf16x8 vb = *(const bf16x8*)&Vs[vrow * 64 + (((g + 4 * kk) ^ (fr & 7)) * 8)];
                accO[n] = __builtin_amdgcn_mfma_f32_16x16x32_bf16(pa, vb, accO[n], 0, 0, 0);
            }
        }
    }

    #pragma unroll
    for (int j = 0; j < 4; ++j) {
        float inv = 1.0f / lrun[j];
        int row = b * Tv + q0 + wave * 16 + g * 4 + j;
        #pragma unroll
        for (int n = 0; n < 4; ++n)
            att[(size_t)row * Cv + h * 64 + n * 16 + fr] =
                __float2bfloat16(accO[n][j] * inv);
    }
}

// ---------------------------------------------------------------------------
// lm-head, 2-phase double-buffered 128x128, fused per-block exp-sum.
// grid 6288 1D, chunked XCD swizzle, row-tiles fastest.
// ---------------------------------------------------------------------------
__launch_bounds__(256)
__global__ void lmhead_kernel(const __hip_bfloat16* __restrict__ A,
                              const __hip_bfloat16* __restrict__ Bt,
                              float* __restrict__ Cf,
                              float* __restrict__ pLse) {
    constexpr int K = Cv, N = Vv;
    __shared__ __hip_bfloat16 As[2][4096];
    __shared__ __hip_bfloat16 Bs[2][4096];
    __shared__ float ps2[2][128];

    int bid = blockIdx.x;
    int nid = (bid & 7) * (NTv * 16 / 8) + (bid >> 3);
    int rowT = nid & 15, colT = nid >> 4;
    int rowBase = rowT * 128, colBase = colT * 128;

    int tid = threadIdx.x, wave = tid >> 6, lane = tid & 63;
    int wr = wave >> 1, wc = wave & 1;

    f32x4 acc[4][4] = {};

    int srow  = wave * 16 + (lane >> 2);
    int skcol = (lane & 3) * 8;
    const __hip_bfloat16* Ap  = A + (size_t)(rowBase + srow) * K + skcol;
    const __hip_bfloat16* Ap2 = Ap + (size_t)64 * K;
    int brow1 = colBase + srow;
    int brow2 = brow1 + 64;
    const __hip_bfloat16* Bp  = Bt + (size_t)brow1 * K + skcol;
    const __hip_bfloat16* Bp2 = Bt + (size_t)(brow2 < N ? brow2 : N - 1) * K + skcol;
    int ldso = wave * 512;

    int aoff = (wr * 64 + (lane & 15)) * 32 + (lane >> 4) * 8;
    int boff = (wc * 64 + (lane & 15)) * 32 + (lane >> 4) * 8;

    // prologue: tile 0 -> buf 0
    gload16(Ap,  &As[0][ldso]);
    gload16(Ap2, &As[0][2048 + ldso]);
    gload16(Bp,  &Bs[0][ldso]);
    gload16(Bp2, &Bs[0][2048 + ldso]);
    Ap += 32; Ap2 += 32; Bp += 32; Bp2 += 32;
    waitvm0_barrier();

    constexpr int nt = K / 32;          // 24
    for (int t = 0; t < nt - 1; ++t) {
        int cur = t & 1, nxt = cur ^ 1;
        gload16(Ap,  &As[nxt][ldso]);
        gload16(Ap2, &As[nxt][2048 + ldso]);
        gload16(Bp,  &Bs[nxt][ldso]);
        gload16(Bp2, &Bs[nxt][2048 + ldso]);
        Ap += 32; Ap2 += 32; Bp += 32; Bp2 += 32;

        bf16x8 av[4], bv[4];
        #pragma unroll
        for (int m = 0; m < 4; ++m) av[m] = *(const bf16x8*)&As[cur][aoff + m * 512];
        #pragma unroll
        for (int n = 0; n < 4; ++n) bv[n] = *(const bf16x8*)&Bs[cur][boff + n * 512];
        #pragma unroll
        for (int m = 0; m < 4; ++m)
            #pragma unroll
            for (int n = 0; n < 4; ++n)
                acc[m][n] = __builtin_amdgcn_mfma_f32_16x16x32_bf16(
                    av[m], bv[n], acc[m][n], 0, 0, 0);
        waitvm0_barrier();
    }
    {
        int cur = (nt - 1) & 1;
        bf16x8 av[4], bv[4];
        #pragma unroll
        for (int m = 0; m < 4; ++m) av[m] = *(const bf16x8*)&As[cur][aoff + m * 512];
        #pragma unroll
        for (int n = 0; n < 4; ++n) bv[n] = *(const bf16x8*)&Bs[cur][boff + n * 512];
        #pragma unroll
        for (int m = 0; m < 4; ++m)
            #pragma unroll
            for (int n = 0; n < 4; ++n)
                acc[m][n] = __builtin_amdgcn_mfma_f32_16x16x32_bf16(
                    av[m], bv[n], acc[m][n], 0, 0, 0);
    }

    int fq = lane >> 4, fr = lane & 15;

    #pragma unroll
    for (int m = 0; m < 4; ++m) {
        #pragma unroll
        for (int j = 0; j < 4; ++j) {
            int row = rowBase + wr * 64 + m * 16 + fq * 4 + j;
            float s = 0.f;
            #pragma unroll
            for (int n = 0; n < 4; ++n) {
                int col = colBase + wc * 64 + n * 16 + fr;
                float v = acc[m][n][j];
                if (col < N) {
                    Cf[(size_t)row * N + col] = v;
                    s += __expf(v);
                }
            }
            #pragma unroll
            for (int off = 1; off < 16; off <<= 1)
                s += __shfl_xor(s, off, 64);
            if (fr == 0)
                ps2[wc][wr * 64 + m * 16 + fq * 4 + j] = s;
        }
    }
    __syncthreads();
    if (tid < 128)
        pLse[(size_t)(rowBase + tid) * NTv + colT] = ps2[0][tid] + ps2[1][tid];
}

// ---------------------------------------------------------------------------
__global__ void plse_reduce_kernel(const float* __restrict__ pLse,
                                   const float* __restrict__ logits,
                                   const int* __restrict__ targets,
                                   float* __restrict__ rloss) {
    int row  = blockIdx.x * 4 + (threadIdx.x >> 6);
    int lane = threadIdx.x & 63;
    const float* pr = pLse + (size_t)row * NTv;
    float l = 0.f;
    for (int i = lane; i < NTv; i += 64) l += pr[i];
    #pragma unroll
    for (int off = 32; off; off >>= 1) l += __shfl_xor(l, off, 64);
    if (lane == 0)
        rloss[row] = logf(l) - logits[(size_t)row * Vv + targets[row]];
}

__global__ void loss_final_kernel(const float* __restrict__ rloss,
                                  float* __restrict__ out, int out_size) {
    float s = 0.f;
    for (int i = threadIdx.x; i < Mv; i += 256) s += rloss[i];
    #pragma unroll
    for (int off = 32; off; off >>= 1) s += __shfl_xor(s, off, 64);
    __shared__ float sw[4];
    int wave = threadIdx.x >> 6, lane = threadIdx.x & 63;
    if (lane == 0) sw[wave] = s;
    __syncthreads();
    if (threadIdx.x == 0)
        out[out_size - 1] = (sw[0] + sw[1] + sw[2] + sw[3]) / (float)Mv;
}

// ---------------------------------------------------------------------------
extern "C" void kernel_launch(void* const* d_in, const int* in_sizes, int n_in,
                              void* d_out, int out_size, void* d_ws, size_t ws_size,
                              hipStream_t stream) {
    const int*   idx     = (const int*)  d_in[0];
    const int*   targets = (const int*)  d_in[1];
    const float* wte     = (const float*)d_in[2];
    const float* wpe     = (const float*)d_in[3];
    const float* ln1_s   = (const float*)d_in[4];
    const float* ln1_b   = (const float*)d_in[5];
    const float* attn_k  = (const float*)d_in[6];
    const float* attn_b  = (const float*)d_in[7];
    const float* aproj_k = (const float*)d_in[8];
    const float* aproj_b = (const float*)d_in[9];
    const float* ln2_s   = (const float*)d_in[10];
    const float* ln2_b   = (const float*)d_in[11];
    const float* fc_k    = (const float*)d_in[12];
    const float* fc_b    = (const float*)d_in[13];
    const float* mproj_k = (const float*)d_in[14];
    const float* mproj_b = (const float*)d_in[15];
    const float* lnf_s   = (const float*)d_in[16];
    const float* lnf_b   = (const float*)d_in[17];

    float* out = (float*)d_out;
    char* ws  = (char*)d_ws;
    char* ob  = (char*)d_out;   // d_out doubles as loop-time scratch

    constexpr size_t NEED = 83568128ULL;
    if (ws_size < NEED) return;

    // ws: live through lm-head
    __hip_bfloat16* wte_bf = (__hip_bfloat16*)(ws + 0);          // 77,194,752
    __hip_bfloat16* h_bf   = (__hip_bfloat16*)(ws + 77194752);   //  3,145,728
    float*          pLse   = (float*)(ws + 80340480);            //  3,219,456
    float*          rloss  = (float*)(ws + 83559936);            //      8,192

    // d_out scratch: all dead before lmhead writes logits
    float*          x      = (float*)(ob + 0);                   //  6,291,456
    __hip_bfloat16* qkv_bf = (__hip_bfloat16*)(ob + 6291456);    //  9,437,184
    __hip_bfloat16* vt_bf  = (__hip_bfloat16*)(ob + 15728640);   //  3,145,728
    __hip_bfloat16* att_bf = (__hip_bfloat16*)(ob + 18874368);   //  3,145,728
    __hip_bfloat16* fco_bf = (__hip_bfloat16*)(ob + 22020096);   // 12,582,912
    __hip_bfloat16* w0     = (__hip_bfloat16*)(ob + 34603008);   //  3,538,944
    __hip_bfloat16* w1     = (__hip_bfloat16*)(ob + 38141952);   //  1,179,648
    __hip_bfloat16* w2     = (__hip_bfloat16*)(ob + 39321600);   //  4,718,592
    __hip_bfloat16* w3     = (__hip_bfloat16*)(ob + 44040192);   //  4,718,592

    embed_kernel<<<Mv, 256, 0, stream>>>(idx, wte, wpe, x);

    for (int l = 0; l < Lv; ++l) {
        wtrans_kernel<<<dim3(72, 24), 256, 0, stream>>>(
            attn_k + (size_t)l * Cv * 2304, w0, Cv, 2304);
        wtrans_kernel<<<dim3(24, 24), 256, 0, stream>>>(
            aproj_k + (size_t)l * Cv * Cv, w1, Cv, Cv);
        wtrans_kernel<<<dim3(96, 24), 256, 0, stream>>>(
            fc_k + (size_t)l * Cv * 3072, w2, Cv, 3072);
        wtrans_kernel<<<dim3(24, 96), 256, 0, stream>>>(
            mproj_k + (size_t)l * 3072 * Cv, w3, 3072, Cv);

        ln_kernel<<<512, 256, 0, stream>>>(x, ln1_s + l * Cv, ln1_b + l * Cv, h_bf);
        gemm_bf16<0, 128><<<dim3(36, 16), 256, 0, stream>>>(
            h_bf, w0, attn_b + l * 2304, nullptr, nullptr, qkv_bf, Mv, 2304, Cv);
        vtrans_kernel<<<dim3(32, 2, 24), 256, 0, stream>>>(qkv_bf, vt_bf);
        attn_kernel<<<dim3(24, 16), 256, 0, stream>>>(qkv_bf, vt_bf, att_bf);
        gemm_bf16<1, 64><<<dim3(12, 32), 256, 0, stream>>>(
            att_bf, w1, aproj_b + l * Cv, x, x, nullptr, Mv, Cv, Cv);
        ln_kernel<<<512, 256, 0, stream>>>(x, ln2_s + l * Cv, ln2_b + l * Cv, h_bf);
        gemm_bf16<2, 128><<<dim3(48, 16), 256, 0, stream>>>(
            h_bf, w2, fc_b + l * 3072, nullptr, nullptr, fco_bf, Mv, 3072, Cv);
        gemm_bf16<1, 64><<<dim3(12, 32), 256, 0, stream>>>(
            fco_bf, w3, mproj_b + l * Cv, x, x, nullptr, Mv, Cv, 3072);
    }

    ln_kernel<<<512, 256, 0, stream>>>(x, lnf_s, lnf_b, h_bf);
    cvt_kernel<<<2048, 256, 0, stream>>>(wte, wte_bf, (Vv * Cv) / 4);
    lmhead_kernel<<<16 * NTv, 256, 0, stream>>>(h_bf, wte_bf, out, pLse);
    plse_reduce_kernel<<<512, 256, 0, stream>>>(pLse, out, targets, rloss);
    loss_final_kernel<<<1, 256, 0, stream>>>(rloss, out, out_size);
}

// Round 7
// 986.756 us; speedup vs baseline: 9.1215x; 1.0773x over previous
//
#include <hip/hip_runtime.h>
#include <hip/hip_bf16.h>
#include <math.h>

typedef __attribute__((ext_vector_type(8))) short bf16x8;
typedef __attribute__((ext_vector_type(4))) float f32x4;

static constexpr int Bv   = 2;
static constexpr int Tv   = 1024;
static constexpr int Cv   = 768;
static constexpr int Hv   = 12;
static constexpr int Lv   = 4;
static constexpr int Vv   = 50257;
static constexpr int Mv   = 2048;
static constexpr int NTv  = 393;          // lm-head col tiles of 128
static constexpr float EPSv = 1e-6f;

// ---------------------------------------------------------------------------
__device__ __forceinline__ void gload16(const void* g, void* l) {
    __builtin_amdgcn_global_load_lds((const __attribute__((address_space(1))) void*)g,
                                     (__attribute__((address_space(3))) void*)l, 16, 0, 0);
}
// counted-vmcnt wait + block barrier, single asm so nothing crosses
template<int N>
__device__ __forceinline__ void waitvm_barrier() {
    if constexpr (N == 0)      asm volatile("s_waitcnt vmcnt(0)\ns_barrier" ::: "memory");
    else if constexpr (N == 2) asm volatile("s_waitcnt vmcnt(2)\ns_barrier" ::: "memory");
    else if constexpr (N == 3) asm volatile("s_waitcnt vmcnt(3)\ns_barrier" ::: "memory");
    else if constexpr (N == 4) asm volatile("s_waitcnt vmcnt(4)\ns_barrier" ::: "memory");
    else if constexpr (N == 6) asm volatile("s_waitcnt vmcnt(6)\ns_barrier" ::: "memory");
    else                       asm volatile("s_waitcnt vmcnt(8)\ns_barrier" ::: "memory");
}
__device__ __forceinline__ void lgkm0_barrier() {
    asm volatile("s_waitcnt lgkmcnt(0)\ns_barrier" ::: "memory");
}

// ---------------------------------------------------------------------------
__global__ void embed_kernel(const int* __restrict__ idx,
                             const float* __restrict__ wte,
                             const float* __restrict__ wpe,
                             float* __restrict__ x) {
    int row = blockIdx.x;
    int t   = row & (Tv - 1);
    int tok = idx[row];
    const float* src = wte + (size_t)tok * Cv;
    const float* pos = wpe + (size_t)t * Cv;
    float* dst = x + (size_t)row * Cv;
    for (int c = threadIdx.x; c < Cv; c += 256)
        dst[c] = src[c] + pos[c];
}

// ---------------------------------------------------------------------------
__device__ __forceinline__ ushort4 pack4bf(float4 v) {
    ushort4 u;
    u.x = __bfloat16_as_ushort(__float2bfloat16(v.x));
    u.y = __bfloat16_as_ushort(__float2bfloat16(v.y));
    u.z = __bfloat16_as_ushort(__float2bfloat16(v.z));
    u.w = __bfloat16_as_ushort(__float2bfloat16(v.w));
    return u;
}

// LayerNorm, one wave per row. fp32 in -> bf16 out. grid 512 x 256.
__global__ void ln_kernel(const float* __restrict__ in,
                          const float* __restrict__ sc,
                          const float* __restrict__ bi,
                          __hip_bfloat16* __restrict__ out) {
    int row  = blockIdx.x * 4 + (threadIdx.x >> 6);
    int lane = threadIdx.x & 63;
    const float4* xr = (const float4*)(in + (size_t)row * Cv);
    float4 a = xr[lane], b = xr[lane + 64], c = xr[lane + 128];
    float sum = a.x + a.y + a.z + a.w + b.x + b.y + b.z + b.w + c.x + c.y + c.z + c.w;
    float sq  = a.x*a.x + a.y*a.y + a.z*a.z + a.w*a.w
              + b.x*b.x + b.y*b.y + b.z*b.z + b.w*b.w
              + c.x*c.x + c.y*c.y + c.z*c.z + c.w*c.w;
    #pragma unroll
    for (int off = 32; off; off >>= 1) {
        sum += __shfl_xor(sum, off, 64);
        sq  += __shfl_xor(sq,  off, 64);
    }
    float mean = sum * (1.0f / Cv);
    float var  = sq * (1.0f / Cv) - mean * mean;
    float rs   = rsqrtf(var + EPSv);
    const float4* s4 = (const float4*)sc;
    const float4* b4 = (const float4*)bi;
    ushort4* orow = (ushort4*)(out + (size_t)row * Cv);
    #pragma unroll
    for (int i = 0; i < 3; ++i) {
        float4 v = (i == 0) ? a : (i == 1) ? b : c;
        float4 s = s4[lane + 64 * i];
        float4 t = b4[lane + 64 * i];
        float4 o;
        o.x = (v.x - mean) * rs * s.x + t.x;
        o.y = (v.y - mean) * rs * s.y + t.y;
        o.z = (v.z - mean) * rs * s.z + t.z;
        o.w = (v.w - mean) * rs * s.w + t.w;
        orow[lane + 64 * i] = pack4bf(o);
    }
}

// ---------------------------------------------------------------------------
// Weight transpose+convert: in fp32 [K][N] -> out bf16 [N][K]
// ---------------------------------------------------------------------------
__global__ void wtrans_kernel(const float* __restrict__ in,
                              __hip_bfloat16* __restrict__ out, int K, int N) {
    __shared__ float tile[32][33];
    int k0 = blockIdx.y * 32, n0 = blockIdx.x * 32;
    int tx = threadIdx.x & 31, ty = threadIdx.x >> 5;   // 32 x 8
    #pragma unroll
    for (int i = 0; i < 4; ++i)
        tile[ty + i * 8][tx] = in[(size_t)(k0 + ty + i * 8) * N + n0 + tx];
    __syncthreads();
    #pragma unroll
    for (int i = 0; i < 4; ++i)
        out[(size_t)(n0 + ty + i * 8) * K + k0 + tx] =
            __float2bfloat16(tile[tx][ty + i * 8]);
}

// ---------------------------------------------------------------------------
// fp32 -> bf16 convert (wte), float4 granularity, grid-stride.
// ---------------------------------------------------------------------------
__global__ void cvt_kernel(const float* __restrict__ in,
                           __hip_bfloat16* __restrict__ out, int n4) {
    int stride = gridDim.x * 256;
    for (int i = blockIdx.x * 256 + threadIdx.x; i < n4; i += stride) {
        float4 v = ((const float4*)in)[i];
        ((ushort4*)out)[i] = pack4bf(v);
    }
}

// ---------------------------------------------------------------------------
// V transpose per layer: qkv_bf[row][h*192+128+d] -> vt[bh][d][t]  (bf16)
// ---------------------------------------------------------------------------
__global__ void vtrans_kernel(const __hip_bfloat16* __restrict__ qkv,
                              __hip_bfloat16* __restrict__ vt) {
    __shared__ __hip_bfloat16 tile[32][33];
    int bh = blockIdx.z;
    int b = bh / Hv, h = bh % Hv;
    int t0 = blockIdx.x * 32, d0 = blockIdx.y * 32;
    int tx = threadIdx.x & 31, ty = threadIdx.x >> 5;
    #pragma unroll
    for (int i = 0; i < 4; ++i)
        tile[ty + i * 8][tx] =
            qkv[(size_t)(b * Tv + t0 + ty + i * 8) * 2304 + h * 192 + 128 + d0 + tx];
    __syncthreads();
    #pragma unroll
    for (int i = 0; i < 4; ++i)
        vt[((size_t)bh * 64 + d0 + ty + i * 8) * Tv + t0 + tx] = tile[tx][ty + i * 8];
}

// ---------------------------------------------------------------------------
// Loop GEMM, 3-deep counted-vmcnt pipeline: C[M,N] = A @ Bt^T + epilogue.
// BM x 64 tile, BK=32, 4 waves (2x2); wave tile (BM/2) x 32.
//   EPI 0: Cb = bf16(acc + bias); EPI 1: Cf = acc + bias + R (in-place);
//   EPI 2: Cb = bf16(gelu(acc + bias))
// ---------------------------------------------------------------------------
template<int EPI, int BM>
__launch_bounds__(256)
__global__ void gemm_bf16(const __hip_bfloat16* __restrict__ A,
                          const __hip_bfloat16* __restrict__ Bt,
                          const float* __restrict__ bias,
                          const float* R, float* Cf,
                          __hip_bfloat16* __restrict__ Cb,
                          int M, int N, int K) {
    constexpr int FM  = BM / 32;          // A frags per wave
    constexpr int NA  = BM / 64;          // 64-row A stage chunks
    constexpr int LPT = NA + 1;           // loads per thread per tile
    __shared__ __hip_bfloat16 As[3][BM * 32];
    __shared__ __hip_bfloat16 Bs[3][64 * 32];
    int tid = threadIdx.x;
    int wave = tid >> 6, lane = tid & 63;
    int wr = wave >> 1, wc = wave & 1;
    int rowBase = blockIdx.y * BM, colBase = blockIdx.x * 64;

    f32x4 acc[FM][2] = {};

    int srow  = wave * 16 + (lane >> 2);
    int skcol = (lane & 3) * 8;
    const __hip_bfloat16* Ap0 = A + (size_t)(rowBase + srow) * K + skcol;
    const __hip_bfloat16* Ap1 = (NA > 1) ? (Ap0 + (size_t)64 * K) : Ap0;
    const __hip_bfloat16* Bp0 = Bt + (size_t)(colBase + srow) * K + skcol;
    int ldso = wave * 512;

    int aoff = (wr * (BM / 2) + (lane & 15)) * 32 + (lane >> 4) * 8;
    int boff = (wc * 32 + (lane & 15)) * 32 + (lane >> 4) * 8;

    auto stage = [&](int buf) {
        gload16(Ap0, &As[buf][ldso]);
        if constexpr (NA > 1) gload16(Ap1, &As[buf][2048 + ldso]);
        gload16(Bp0, &Bs[buf][ldso]);
        Ap0 += 32;
        if constexpr (NA > 1) Ap1 += 32;
        Bp0 += 32;
    };

    stage(0); stage(1); stage(2);

    int nt = K / 32;
    int cur = 0;
    for (int t = 0; t < nt; ++t) {
        if (t < nt - 2)       waitvm_barrier<2 * LPT>();   // tile t resident
        else if (t == nt - 2) waitvm_barrier<LPT>();
        else                  waitvm_barrier<0>();

        bf16x8 av[FM], bv[2];
        #pragma unroll
        for (int m = 0; m < FM; ++m) av[m] = *(const bf16x8*)&As[cur][aoff + m * 512];
        #pragma unroll
        for (int n = 0; n < 2; ++n)  bv[n] = *(const bf16x8*)&Bs[cur][boff + n * 512];
        lgkm0_barrier();                                   // buffer cur is free

        if (t + 3 < nt) stage(cur);

        #pragma unroll
        for (int m = 0; m < FM; ++m)
            #pragma unroll
            for (int n = 0; n < 2; ++n)
                acc[m][n] = __builtin_amdgcn_mfma_f32_16x16x32_bf16(
                    av[m], bv[n], acc[m][n], 0, 0, 0);
        cur = (cur == 2) ? 0 : cur + 1;
    }

    int fq = lane >> 4, fr = lane & 15;
    #pragma unroll
    for (int m = 0; m < FM; ++m) {
        #pragma unroll
        for (int n = 0; n < 2; ++n) {
            f32x4 v = acc[m][n];
            int col = colBase + wc * 32 + n * 16 + fr;
            #pragma unroll
            for (int j = 0; j < 4; ++j) {
                int row = rowBase + wr * (BM / 2) + m * 16 + fq * 4 + j;
                float val = v[j] + bias[col];
                if (EPI == 1) {
                    val += R[(size_t)row * N + col];
                    Cf[(size_t)row * N + col] = val;
                } else {
                    if (EPI == 2) {
                        float u = val;
                        float cc = 0.7978845608028654f * (u + 0.044715f * u * u * u);
                        val = 0.5f * u * (1.0f + tanhf(cc));
                    }
                    Cb[(size_t)row * N + col] = __float2bfloat16(val);
                }
            }
        }
    }
}

// ---------------------------------------------------------------------------
// MFMA flash attention (unchanged from round 5).
// ---------------------------------------------------------------------------
__launch_bounds__(256)
__global__ void attn_kernel(const __hip_bfloat16* __restrict__ qkv,
                            const __hip_bfloat16* __restrict__ vt,
                            __hip_bfloat16* __restrict__ att) {
    __shared__ __hip_bfloat16 Qs[64 * 64];
    __shared__ __hip_bfloat16 Ks[64 * 64];
    __shared__ __hip_bfloat16 Vs[64 * 64];   // Vs[d][k]
    __shared__ __hip_bfloat16 Ps[64 * 64];
    int bh = blockIdx.x;
    int b = bh / Hv, h = bh % Hv;
    int qt = (int)gridDim.y - 1 - (int)blockIdx.y;
    int q0 = qt * 64;
    int tid = threadIdx.x, wave = tid >> 6, lane = tid & 63;
    int g = lane >> 4, fr = lane & 15;
    int srow8 = lane >> 3, sc8 = lane & 7;

    const __hip_bfloat16* qbase = qkv + (size_t)(b * Tv + q0) * 2304 + h * 192;
    #pragma unroll
    for (int i = 0; i < 2; ++i) {
        int row = wave * 16 + i * 8 + srow8;
        gload16(qbase + (size_t)row * 2304 + ((sc8 ^ (row & 7)) * 8),
                Qs + (wave * 16 + i * 8) * 64);
    }

    f32x4 accO[4] = {};
    float mrun[4] = {-1e30f, -1e30f, -1e30f, -1e30f};
    float lrun[4] = {0.f, 0.f, 0.f, 0.f};

    for (int kv = 0; kv <= qt; ++kv) {
        int s0 = kv * 64;
        __syncthreads();
        const __hip_bfloat16* kbase = qkv + (size_t)(b * Tv + s0) * 2304 + h * 192 + 64;
        const __hip_bfloat16* vbase = vt + (size_t)bh * 64 * Tv + s0;
        #pragma unroll
        for (int i = 0; i < 2; ++i) {
            int row = wave * 16 + i * 8 + srow8;
            gload16(kbase + (size_t)row * 2304 + ((sc8 ^ (row & 7)) * 8),
                    Ks + (wave * 16 + i * 8) * 64);
            gload16(vbase + (size_t)row * Tv + ((sc8 ^ (row & 7)) * 8),
                    Vs + (wave * 16 + i * 8) * 64);
        }
        __syncthreads();

        f32x4 s4[4] = {};
        #pragma unroll
        for (int kk = 0; kk < 2; ++kk) {
            int qrow = wave * 16 + fr;
            bf16x8 qa = *(const bf16x8*)&Qs[qrow * 64 + (((g + 4 * kk) ^ (fr & 7)) * 8)];
            #pragma unroll
            for (int n = 0; n < 4; ++n) {
                int krow = n * 16 + fr;
                bf16x8 kb = *(const bf16x8*)&Ks[krow * 64 + (((g + 4 * kk) ^ (fr & 7)) * 8)];
                s4[n] = __builtin_amdgcn_mfma_f32_16x16x32_bf16(qa, kb, s4[n], 0, 0, 0);
            }
        }

        bool dia = (kv == qt);
        #pragma unroll
        for (int j = 0; j < 4; ++j) {
            int qg = q0 + wave * 16 + g * 4 + j;
            float sj[4], mx = -1e30f;
            #pragma unroll
            for (int n = 0; n < 4; ++n) {
                float v = s4[n][j] * 0.125f;
                if (dia && (s0 + n * 16 + fr) > qg) v = -1e30f;
                sj[n] = v;
                mx = fmaxf(mx, v);
            }
            #pragma unroll
            for (int off = 1; off < 16; off <<= 1)
                mx = fmaxf(mx, __shfl_xor(mx, off, 64));
            float mnew = fmaxf(mrun[j], mx);
            float ps = 0.f;
            unsigned short pb[4];
            #pragma unroll
            for (int n = 0; n < 4; ++n) {
                float p = __expf(sj[n] - mnew);
                __hip_bfloat16 pc = __float2bfloat16(p);
                pb[n] = __bfloat16_as_ushort(pc);
                ps += __bfloat162float(pc);
            }
            #pragma unroll
            for (int off = 1; off < 16; off <<= 1)
                ps += __shfl_xor(ps, off, 64);
            float cr = __expf(mrun[j] - mnew);
            lrun[j] = lrun[j] * cr + ps;
            mrun[j] = mnew;
            int prow = wave * 16 + g * 4 + j;
            #pragma unroll
            for (int n = 0; n < 4; ++n) {
                int byteoff = (32 * n + 2 * fr) ^ ((prow & 7) << 4);
                ((unsigned short*)Ps)[prow * 64 + (byteoff >> 1)] = pb[n];
            }
            #pragma unroll
            for (int n = 0; n < 4; ++n) accO[n][j] *= cr;
        }
        __syncthreads();

        #pragma unroll
        for (int kk = 0; kk < 2; ++kk) {
            int prow = wave * 16 + fr;
            bf16x8 pa = *(const bf16x8*)&Ps[prow * 64 + (((g + 4 * kk) ^ (fr & 7)) * 8)];
            #pragma unroll
            for (int n = 0; n < 4; ++n) {
                int vrow = n * 16 + fr;
                bf16x8 vb = *(const bf16x8*)&Vs[vrow * 64 + (((g + 4 * kk) ^ (fr & 7)) * 8)];
                accO[n] = __builtin_amdgcn_mfma_f32_16x16x32_bf16(pa, vb, accO[n], 0, 0, 0);
            }
        }
    }

    #pragma unroll
    for (int j = 0; j < 4; ++j) {
        float inv = 1.0f / lrun[j];
        int row = b * Tv + q0 + wave * 16 + g * 4 + j;
        #pragma unroll
        for (int n = 0; n < 4; ++n)
            att[(size_t)row * Cv + h * 64 + n * 16 + fr] =
                __float2bfloat16(accO[n][j] * inv);
    }
}

// ---------------------------------------------------------------------------
// lm-head, 3-deep counted-vmcnt pipeline, 128x128 tile, fused exp-sum.
// grid 6288 1D, chunked XCD swizzle, row-tiles fastest.
// ---------------------------------------------------------------------------
__launch_bounds__(256)
__global__ void lmhead_kernel(const __hip_bfloat16* __restrict__ A,
                              const __hip_bfloat16* __restrict__ Bt,
                              float* __restrict__ Cf,
                              float* __restrict__ pLse) {
    constexpr int K = Cv, N = Vv;
    __shared__ __hip_bfloat16 As[3][4096];
    __shared__ __hip_bfloat16 Bs[3][4096];
    __shared__ float ps2[2][128];

    int bid = blockIdx.x;
    int nid = (bid & 7) * (NTv * 16 / 8) + (bid >> 3);
    int rowT = nid & 15, colT = nid >> 4;
    int rowBase = rowT * 128, colBase = colT * 128;

    int tid = threadIdx.x, wave = tid >> 6, lane = tid & 63;
    int wr = wave >> 1, wc = wave & 1;

    f32x4 acc[4][4] = {};

    int srow  = wave * 16 + (lane >> 2);
    int skcol = (lane & 3) * 8;
    const __hip_bfloat16* Ap  = A + (size_t)(rowBase + srow) * K + skcol;
    const __hip_bfloat16* Ap2 = Ap + (size_t)64 * K;
    int brow1 = colBase + srow;
    int brow2 = brow1 + 64;
    const __hip_bfloat16* Bp  = Bt + (size_t)brow1 * K + skcol;
    const __hip_bfloat16* Bp2 = Bt + (size_t)(brow2 < N ? brow2 : N - 1) * K + skcol;
    int ldso = wave * 512;

    int aoff = (wr * 64 + (lane & 15)) * 32 + (lane >> 4) * 8;
    int boff = (wc * 64 + (lane & 15)) * 32 + (lane >> 4) * 8;

    auto stage = [&](int buf) {
        gload16(Ap,  &As[buf][ldso]);
        gload16(Ap2, &As[buf][2048 + ldso]);
        gload16(Bp,  &Bs[buf][ldso]);
        gload16(Bp2, &Bs[buf][2048 + ldso]);
        Ap += 32; Ap2 += 32; Bp += 32; Bp2 += 32;
    };

    stage(0); stage(1); stage(2);

    constexpr int nt = K / 32;          // 24
    int cur = 0;
    for (int t = 0; t < nt; ++t) {
        if (t < nt - 2)       waitvm_barrier<8>();
        else if (t == nt - 2) waitvm_barrier<4>();
        else                  waitvm_barrier<0>();

        bf16x8 av[4], bv[4];
        #pragma unroll
        for (int m = 0; m < 4; ++m) av[m] = *(const bf16x8*)&As[cur][aoff + m * 512];
        #pragma unroll
        for (int n = 0; n < 4; ++n) bv[n] = *(const bf16x8*)&Bs[cur][boff + n * 512];
        lgkm0_barrier();

        if (t + 3 < nt) stage(cur);

        #pragma unroll
        for (int m = 0; m < 4; ++m)
            #pragma unroll
            for (int n = 0; n < 4; ++n)
                acc[m][n] = __builtin_amdgcn_mfma_f32_16x16x32_bf16(
                    av[m], bv[n], acc[m][n], 0, 0, 0);
        cur = (cur == 2) ? 0 : cur + 1;
    }

    int fq = lane >> 4, fr = lane & 15;

    #pragma unroll
    for (int m = 0; m < 4; ++m) {
        #pragma unroll
        for (int j = 0; j < 4; ++j) {
            int row = rowBase + wr * 64 + m * 16 + fq * 4 + j;
            float s = 0.f;
            #pragma unroll
            for (int n = 0; n < 4; ++n) {
                int col = colBase + wc * 64 + n * 16 + fr;
                float v = acc[m][n][j];
                if (col < N) {
                    Cf[(size_t)row * N + col] = v;
                    s += __expf(v);
                }
            }
            #pragma unroll
            for (int off = 1; off < 16; off <<= 1)
                s += __shfl_xor(s, off, 64);
            if (fr == 0)
                ps2[wc][wr * 64 + m * 16 + fq * 4 + j] = s;
        }
    }
    __syncthreads();
    if (tid < 128)
        pLse[(size_t)(rowBase + tid) * NTv + colT] = ps2[0][tid] + ps2[1][tid];
}

// ---------------------------------------------------------------------------
__global__ void plse_reduce_kernel(const float* __restrict__ pLse,
                                   const float* __restrict__ logits,
                                   const int* __restrict__ targets,
                                   float* __restrict__ rloss) {
    int row  = blockIdx.x * 4 + (threadIdx.x >> 6);
    int lane = threadIdx.x & 63;
    const float* pr = pLse + (size_t)row * NTv;
    float l = 0.f;
    for (int i = lane; i < NTv; i += 64) l += pr[i];
    #pragma unroll
    for (int off = 32; off; off >>= 1) l += __shfl_xor(l, off, 64);
    if (lane == 0)
        rloss[row] = logf(l) - logits[(size_t)row * Vv + targets[row]];
}

__global__ void loss_final_kernel(const float* __restrict__ rloss,
                                  float* __restrict__ out, int out_size) {
    float s = 0.f;
    for (int i = threadIdx.x; i < Mv; i += 256) s += rloss[i];
    #pragma unroll
    for (int off = 32; off; off >>= 1) s += __shfl_xor(s, off, 64);
    __shared__ float sw[4];
    int wave = threadIdx.x >> 6, lane = threadIdx.x & 63;
    if (lane == 0) sw[wave] = s;
    __syncthreads();
    if (threadIdx.x == 0)
        out[out_size - 1] = (sw[0] + sw[1] + sw[2] + sw[3]) / (float)Mv;
}

// ---------------------------------------------------------------------------
extern "C" void kernel_launch(void* const* d_in, const int* in_sizes, int n_in,
                              void* d_out, int out_size, void* d_ws, size_t ws_size,
                              hipStream_t stream) {
    const int*   idx     = (const int*)  d_in[0];
    const int*   targets = (const int*)  d_in[1];
    const float* wte     = (const float*)d_in[2];
    const float* wpe     = (const float*)d_in[3];
    const float* ln1_s   = (const float*)d_in[4];
    const float* ln1_b   = (const float*)d_in[5];
    const float* attn_k  = (const float*)d_in[6];
    const float* attn_b  = (const float*)d_in[7];
    const float* aproj_k = (const float*)d_in[8];
    const float* aproj_b = (const float*)d_in[9];
    const float* ln2_s   = (const float*)d_in[10];
    const float* ln2_b   = (const float*)d_in[11];
    const float* fc_k    = (const float*)d_in[12];
    const float* fc_b    = (const float*)d_in[13];
    const float* mproj_k = (const float*)d_in[14];
    const float* mproj_b = (const float*)d_in[15];
    const float* lnf_s   = (const float*)d_in[16];
    const float* lnf_b   = (const float*)d_in[17];

    float* out = (float*)d_out;
    char* ws  = (char*)d_ws;
    char* ob  = (char*)d_out;   // d_out doubles as loop-time scratch

    constexpr size_t NEED = 83568128ULL;
    if (ws_size < NEED) return;

    // ws: live through lm-head
    __hip_bfloat16* wte_bf = (__hip_bfloat16*)(ws + 0);          // 77,194,752
    __hip_bfloat16* h_bf   = (__hip_bfloat16*)(ws + 77194752);   //  3,145,728
    float*          pLse   = (float*)(ws + 80340480);            //  3,219,456
    float*          rloss  = (float*)(ws + 83559936);            //      8,192

    // d_out scratch: all dead before lmhead writes logits
    float*          x      = (float*)(ob + 0);                   //  6,291,456
    __hip_bfloat16* qkv_bf = (__hip_bfloat16*)(ob + 6291456);    //  9,437,184
    __hip_bfloat16* vt_bf  = (__hip_bfloat16*)(ob + 15728640);   //  3,145,728
    __hip_bfloat16* att_bf = (__hip_bfloat16*)(ob + 18874368);   //  3,145,728
    __hip_bfloat16* fco_bf = (__hip_bfloat16*)(ob + 22020096);   // 12,582,912
    __hip_bfloat16* w0     = (__hip_bfloat16*)(ob + 34603008);   //  3,538,944
    __hip_bfloat16* w1     = (__hip_bfloat16*)(ob + 38141952);   //  1,179,648
    __hip_bfloat16* w2     = (__hip_bfloat16*)(ob + 39321600);   //  4,718,592
    __hip_bfloat16* w3     = (__hip_bfloat16*)(ob + 44040192);   //  4,718,592

    embed_kernel<<<Mv, 256, 0, stream>>>(idx, wte, wpe, x);

    for (int l = 0; l < Lv; ++l) {
        wtrans_kernel<<<dim3(72, 24), 256, 0, stream>>>(
            attn_k + (size_t)l * Cv * 2304, w0, Cv, 2304);
        wtrans_kernel<<<dim3(24, 24), 256, 0, stream>>>(
            aproj_k + (size_t)l * Cv * Cv, w1, Cv, Cv);
        wtrans_kernel<<<dim3(96, 24), 256, 0, stream>>>(
            fc_k + (size_t)l * Cv * 3072, w2, Cv, 3072);
        wtrans_kernel<<<dim3(24, 96), 256, 0, stream>>>(
            mproj_k + (size_t)l * 3072 * Cv, w3, 3072, Cv);

        ln_kernel<<<512, 256, 0, stream>>>(x, ln1_s + l * Cv, ln1_b + l * Cv, h_bf);
        gemm_bf16<0, 128><<<dim3(36, 16), 256, 0, stream>>>(
            h_bf, w0, attn_b + l * 2304, nullptr, nullptr, qkv_bf, Mv, 2304, Cv);
        vtrans_kernel<<<dim3(32, 2, 24), 256, 0, stream>>>(qkv_bf, vt_bf);
        attn_kernel<<<dim3(24, 16), 256, 0, stream>>>(qkv_bf, vt_bf, att_bf);
        gemm_bf16<1, 64><<<dim3(12, 32), 256, 0, stream>>>(
            att_bf, w1, aproj_b + l * Cv, x, x, nullptr, Mv, Cv, Cv);
        ln_kernel<<<512, 256, 0, stream>>>(x, ln2_s + l * Cv, ln2_b + l * Cv, h_bf);
        gemm_bf16<2, 128><<<dim3(48, 16), 256, 0, stream>>>(
            h_bf, w2, fc_b + l * 3072, nullptr, nullptr, fco_bf, Mv, 3072, Cv);
        gemm_bf16<1, 64><<<dim3(12, 32), 256, 0, stream>>>(
            fco_bf, w3, mproj_b + l * Cv, x, x, nullptr, Mv, Cv, 3072);
    }

    ln_kernel<<<512, 256, 0, stream>>>(x, lnf_s, lnf_b, h_bf);
    cvt_kernel<<<2048, 256, 0, stream>>>(wte, wte_bf, (Vv * Cv) / 4);
    lmhead_kernel<<<16 * NTv, 256, 0, stream>>>(h_bf, wte_bf, out, pLse);
    plse_reduce_kernel<<<512, 256, 0, stream>>>(pLse, out, targets, rloss);
    loss_final_kernel<<<1, 256, 0, stream>>>(rloss, out, out_size);
}

// Round 8
// 942.134 us; speedup vs baseline: 9.5535x; 1.0474x over previous
//
#include <hip/hip_runtime.h>
#include <hip/hip_bf16.h>
#include <math.h>

typedef __attribute__((ext_vector_type(8))) short bf16x8;
typedef __attribute__((ext_vector_type(4))) float f32x4;

static constexpr int Bv   = 2;
static constexpr int Tv   = 1024;
static constexpr int Cv   = 768;
static constexpr int Hv   = 12;
static constexpr int Lv   = 4;
static constexpr int Vv   = 50257;
static constexpr int Mv   = 2048;
static constexpr int NT2  = 197;          // lm-head col tiles of 256
static constexpr float EPSv = 1e-6f;

// ---------------------------------------------------------------------------
__device__ __forceinline__ void gload16(const void* g, void* l) {
    __builtin_amdgcn_global_load_lds((const __attribute__((address_space(1))) void*)g,
                                     (__attribute__((address_space(3))) void*)l, 16, 0, 0);
}
template<int N>
__device__ __forceinline__ void waitvm_barrier() {
    if constexpr (N == 0)      asm volatile("s_waitcnt vmcnt(0)\ns_barrier" ::: "memory");
    else if constexpr (N == 2) asm volatile("s_waitcnt vmcnt(2)\ns_barrier" ::: "memory");
    else if constexpr (N == 3) asm volatile("s_waitcnt vmcnt(3)\ns_barrier" ::: "memory");
    else if constexpr (N == 4) asm volatile("s_waitcnt vmcnt(4)\ns_barrier" ::: "memory");
    else if constexpr (N == 6) asm volatile("s_waitcnt vmcnt(6)\ns_barrier" ::: "memory");
    else                       asm volatile("s_waitcnt vmcnt(8)\ns_barrier" ::: "memory");
}
__device__ __forceinline__ void lgkm0_barrier() {
    asm volatile("s_waitcnt lgkmcnt(0)\ns_barrier" ::: "memory");
}

// ---------------------------------------------------------------------------
__global__ void embed_kernel(const int* __restrict__ idx,
                             const float* __restrict__ wte,
                             const float* __restrict__ wpe,
                             float* __restrict__ x) {
    int row = blockIdx.x;
    int t   = row & (Tv - 1);
    int tok = idx[row];
    const float* src = wte + (size_t)tok * Cv;
    const float* pos = wpe + (size_t)t * Cv;
    float* dst = x + (size_t)row * Cv;
    for (int c = threadIdx.x; c < Cv; c += 256)
        dst[c] = src[c] + pos[c];
}

// ---------------------------------------------------------------------------
__device__ __forceinline__ ushort4 pack4bf(float4 v) {
    ushort4 u;
    u.x = __bfloat16_as_ushort(__float2bfloat16(v.x));
    u.y = __bfloat16_as_ushort(__float2bfloat16(v.y));
    u.z = __bfloat16_as_ushort(__float2bfloat16(v.z));
    u.w = __bfloat16_as_ushort(__float2bfloat16(v.w));
    return u;
}

// LayerNorm, one wave per row. fp32 in -> bf16 out. grid 512 x 256.
__global__ void ln_kernel(const float* __restrict__ in,
                          const float* __restrict__ sc,
                          const float* __restrict__ bi,
                          __hip_bfloat16* __restrict__ out) {
    int row  = blockIdx.x * 4 + (threadIdx.x >> 6);
    int lane = threadIdx.x & 63;
    const float4* xr = (const float4*)(in + (size_t)row * Cv);
    float4 a = xr[lane], b = xr[lane + 64], c = xr[lane + 128];
    float sum = a.x + a.y + a.z + a.w + b.x + b.y + b.z + b.w + c.x + c.y + c.z + c.w;
    float sq  = a.x*a.x + a.y*a.y + a.z*a.z + a.w*a.w
              + b.x*b.x + b.y*b.y + b.z*b.z + b.w*b.w
              + c.x*c.x + c.y*c.y + c.z*c.z + c.w*c.w;
    #pragma unroll
    for (int off = 32; off; off >>= 1) {
        sum += __shfl_xor(sum, off, 64);
        sq  += __shfl_xor(sq,  off, 64);
    }
    float mean = sum * (1.0f / Cv);
    float var  = sq * (1.0f / Cv) - mean * mean;
    float rs   = rsqrtf(var + EPSv);
    const float4* s4 = (const float4*)sc;
    const float4* b4 = (const float4*)bi;
    ushort4* orow = (ushort4*)(out + (size_t)row * Cv);
    #pragma unroll
    for (int i = 0; i < 3; ++i) {
        float4 v = (i == 0) ? a : (i == 1) ? b : c;
        float4 s = s4[lane + 64 * i];
        float4 t = b4[lane + 64 * i];
        float4 o;
        o.x = (v.x - mean) * rs * s.x + t.x;
        o.y = (v.y - mean) * rs * s.y + t.y;
        o.z = (v.z - mean) * rs * s.z + t.z;
        o.w = (v.w - mean) * rs * s.w + t.w;
        orow[lane + 64 * i] = pack4bf(o);
    }
}

// ---------------------------------------------------------------------------
// Weight transpose+convert, batched over layers (grid.z):
// in fp32 [K][N] -> out bf16 [N][K]
// ---------------------------------------------------------------------------
__global__ void wtrans_kernel(const float* __restrict__ in,
                              __hip_bfloat16* __restrict__ out, int K, int N,
                              size_t inLS, size_t outLS) {
    __shared__ float tile[32][33];
    in  += (size_t)blockIdx.z * inLS;
    out += (size_t)blockIdx.z * outLS;
    int k0 = blockIdx.y * 32, n0 = blockIdx.x * 32;
    int tx = threadIdx.x & 31, ty = threadIdx.x >> 5;   // 32 x 8
    #pragma unroll
    for (int i = 0; i < 4; ++i)
        tile[ty + i * 8][tx] = in[(size_t)(k0 + ty + i * 8) * N + n0 + tx];
    __syncthreads();
    #pragma unroll
    for (int i = 0; i < 4; ++i)
        out[(size_t)(n0 + ty + i * 8) * K + k0 + tx] =
            __float2bfloat16(tile[tx][ty + i * 8]);
}

// ---------------------------------------------------------------------------
// fp32 -> bf16 convert (wte), float4 granularity, grid-stride.
// ---------------------------------------------------------------------------
__global__ void cvt_kernel(const float* __restrict__ in,
                           __hip_bfloat16* __restrict__ out, int n4) {
    int stride = gridDim.x * 256;
    for (int i = blockIdx.x * 256 + threadIdx.x; i < n4; i += stride) {
        float4 v = ((const float4*)in)[i];
        ((ushort4*)out)[i] = pack4bf(v);
    }
}

// ---------------------------------------------------------------------------
// V transpose per layer: qkv_bf[row][h*192+128+d] -> vt[bh][d][t]  (bf16)
// ---------------------------------------------------------------------------
__global__ void vtrans_kernel(const __hip_bfloat16* __restrict__ qkv,
                              __hip_bfloat16* __restrict__ vt) {
    __shared__ __hip_bfloat16 tile[32][33];
    int bh = blockIdx.z;
    int b = bh / Hv, h = bh % Hv;
    int t0 = blockIdx.x * 32, d0 = blockIdx.y * 32;
    int tx = threadIdx.x & 31, ty = threadIdx.x >> 5;
    #pragma unroll
    for (int i = 0; i < 4; ++i)
        tile[ty + i * 8][tx] =
            qkv[(size_t)(b * Tv + t0 + ty + i * 8) * 2304 + h * 192 + 128 + d0 + tx];
    __syncthreads();
    #pragma unroll
    for (int i = 0; i < 4; ++i)
        vt[((size_t)bh * 64 + d0 + ty + i * 8) * Tv + t0 + tx] = tile[tx][ty + i * 8];
}

// ---------------------------------------------------------------------------
// Loop GEMM, 3-deep counted-vmcnt pipeline: C[M,N] = A @ Bt^T + epilogue.
//   EPI 0: Cb = bf16(acc + bias); EPI 1: Cf = acc + bias + R (in-place);
//   EPI 2: Cb = bf16(gelu(acc + bias))
// ---------------------------------------------------------------------------
template<int EPI, int BM>
__launch_bounds__(256)
__global__ void gemm_bf16(const __hip_bfloat16* __restrict__ A,
                          const __hip_bfloat16* __restrict__ Bt,
                          const float* __restrict__ bias,
                          const float* R, float* Cf,
                          __hip_bfloat16* __restrict__ Cb,
                          int M, int N, int K) {
    constexpr int FM  = BM / 32;
    constexpr int NA  = BM / 64;
    constexpr int LPT = NA + 1;
    __shared__ __hip_bfloat16 As[3][BM * 32];
    __shared__ __hip_bfloat16 Bs[3][64 * 32];
    int tid = threadIdx.x;
    int wave = tid >> 6, lane = tid & 63;
    int wr = wave >> 1, wc = wave & 1;
    int rowBase = blockIdx.y * BM, colBase = blockIdx.x * 64;

    f32x4 acc[FM][2] = {};

    int srow  = wave * 16 + (lane >> 2);
    int skcol = (lane & 3) * 8;
    const __hip_bfloat16* Ap0 = A + (size_t)(rowBase + srow) * K + skcol;
    const __hip_bfloat16* Ap1 = (NA > 1) ? (Ap0 + (size_t)64 * K) : Ap0;
    const __hip_bfloat16* Bp0 = Bt + (size_t)(colBase + srow) * K + skcol;
    int ldso = wave * 512;

    int aoff = (wr * (BM / 2) + (lane & 15)) * 32 + (lane >> 4) * 8;
    int boff = (wc * 32 + (lane & 15)) * 32 + (lane >> 4) * 8;

    auto stage = [&](int buf) {
        gload16(Ap0, &As[buf][ldso]);
        if constexpr (NA > 1) gload16(Ap1, &As[buf][2048 + ldso]);
        gload16(Bp0, &Bs[buf][ldso]);
        Ap0 += 32;
        if constexpr (NA > 1) Ap1 += 32;
        Bp0 += 32;
    };

    stage(0); stage(1); stage(2);

    int nt = K / 32;
    int cur = 0;
    for (int t = 0; t < nt; ++t) {
        if (t < nt - 2)       waitvm_barrier<2 * LPT>();
        else if (t == nt - 2) waitvm_barrier<LPT>();
        else                  waitvm_barrier<0>();

        bf16x8 av[FM], bv[2];
        #pragma unroll
        for (int m = 0; m < FM; ++m) av[m] = *(const bf16x8*)&As[cur][aoff + m * 512];
        #pragma unroll
        for (int n = 0; n < 2; ++n)  bv[n] = *(const bf16x8*)&Bs[cur][boff + n * 512];
        lgkm0_barrier();

        if (t + 3 < nt) stage(cur);

        #pragma unroll
        for (int m = 0; m < FM; ++m)
            #pragma unroll
            for (int n = 0; n < 2; ++n)
                acc[m][n] = __builtin_amdgcn_mfma_f32_16x16x32_bf16(
                    av[m], bv[n], acc[m][n], 0, 0, 0);
        cur = (cur == 2) ? 0 : cur + 1;
    }

    int fq = lane >> 4, fr = lane & 15;
    #pragma unroll
    for (int m = 0; m < FM; ++m) {
        #pragma unroll
        for (int n = 0; n < 2; ++n) {
            f32x4 v = acc[m][n];
            int col = colBase + wc * 32 + n * 16 + fr;
            #pragma unroll
            for (int j = 0; j < 4; ++j) {
                int row = rowBase + wr * (BM / 2) + m * 16 + fq * 4 + j;
                float val = v[j] + bias[col];
                if (EPI == 1) {
                    val += R[(size_t)row * N + col];
                    Cf[(size_t)row * N + col] = val;
                } else {
                    if (EPI == 2) {
                        float u = val;
                        float cc = 0.7978845608028654f * (u + 0.044715f * u * u * u);
                        val = 0.5f * u * (1.0f + tanhf(cc));
                    }
                    Cb[(size_t)row * N + col] = __float2bfloat16(val);
                }
            }
        }
    }
}

// ---------------------------------------------------------------------------
// MFMA flash attention (unchanged).
// ---------------------------------------------------------------------------
__launch_bounds__(256)
__global__ void attn_kernel(const __hip_bfloat16* __restrict__ qkv,
                            const __hip_bfloat16* __restrict__ vt,
                            __hip_bfloat16* __restrict__ att) {
    __shared__ __hip_bfloat16 Qs[64 * 64];
    __shared__ __hip_bfloat16 Ks[64 * 64];
    __shared__ __hip_bfloat16 Vs[64 * 64];   // Vs[d][k]
    __shared__ __hip_bfloat16 Ps[64 * 64];
    int bh = blockIdx.x;
    int b = bh / Hv, h = bh % Hv;
    int qt = (int)gridDim.y - 1 - (int)blockIdx.y;
    int q0 = qt * 64;
    int tid = threadIdx.x, wave = tid >> 6, lane = tid & 63;
    int g = lane >> 4, fr = lane & 15;
    int srow8 = lane >> 3, sc8 = lane & 7;

    const __hip_bfloat16* qbase = qkv + (size_t)(b * Tv + q0) * 2304 + h * 192;
    #pragma unroll
    for (int i = 0; i < 2; ++i) {
        int row = wave * 16 + i * 8 + srow8;
        gload16(qbase + (size_t)row * 2304 + ((sc8 ^ (row & 7)) * 8),
                Qs + (wave * 16 + i * 8) * 64);
    }

    f32x4 accO[4] = {};
    float mrun[4] = {-1e30f, -1e30f, -1e30f, -1e30f};
    float lrun[4] = {0.f, 0.f, 0.f, 0.f};

    for (int kv = 0; kv <= qt; ++kv) {
        int s0 = kv * 64;
        __syncthreads();
        const __hip_bfloat16* kbase = qkv + (size_t)(b * Tv + s0) * 2304 + h * 192 + 64;
        const __hip_bfloat16* vbase = vt + (size_t)bh * 64 * Tv + s0;
        #pragma unroll
        for (int i = 0; i < 2; ++i) {
            int row = wave * 16 + i * 8 + srow8;
            gload16(kbase + (size_t)row * 2304 + ((sc8 ^ (row & 7)) * 8),
                    Ks + (wave * 16 + i * 8) * 64);
            gload16(vbase + (size_t)row * Tv + ((sc8 ^ (row & 7)) * 8),
                    Vs + (wave * 16 + i * 8) * 64);
        }
        __syncthreads();

        f32x4 s4[4] = {};
        #pragma unroll
        for (int kk = 0; kk < 2; ++kk) {
            int qrow = wave * 16 + fr;
            bf16x8 qa = *(const bf16x8*)&Qs[qrow * 64 + (((g + 4 * kk) ^ (fr & 7)) * 8)];
            #pragma unroll
            for (int n = 0; n < 4; ++n) {
                int krow = n * 16 + fr;
                bf16x8 kb = *(const bf16x8*)&Ks[krow * 64 + (((g + 4 * kk) ^ (fr & 7)) * 8)];
                s4[n] = __builtin_amdgcn_mfma_f32_16x16x32_bf16(qa, kb, s4[n], 0, 0, 0);
            }
        }

        bool dia = (kv == qt);
        #pragma unroll
        for (int j = 0; j < 4; ++j) {
            int qg = q0 + wave * 16 + g * 4 + j;
            float sj[4], mx = -1e30f;
            #pragma unroll
            for (int n = 0; n < 4; ++n) {
                float v = s4[n][j] * 0.125f;
                if (dia && (s0 + n * 16 + fr) > qg) v = -1e30f;
                sj[n] = v;
                mx = fmaxf(mx, v);
            }
            #pragma unroll
            for (int off = 1; off < 16; off <<= 1)
                mx = fmaxf(mx, __shfl_xor(mx, off, 64));
            float mnew = fmaxf(mrun[j], mx);
            float ps = 0.f;
            unsigned short pb[4];
            #pragma unroll
            for (int n = 0; n < 4; ++n) {
                float p = __expf(sj[n] - mnew);
                __hip_bfloat16 pc = __float2bfloat16(p);
                pb[n] = __bfloat16_as_ushort(pc);
                ps += __bfloat162float(pc);
            }
            #pragma unroll
            for (int off = 1; off < 16; off <<= 1)
                ps += __shfl_xor(ps, off, 64);
            float cr = __expf(mrun[j] - mnew);
            lrun[j] = lrun[j] * cr + ps;
            mrun[j] = mnew;
            int prow = wave * 16 + g * 4 + j;
            #pragma unroll
            for (int n = 0; n < 4; ++n) {
                int byteoff = (32 * n + 2 * fr) ^ ((prow & 7) << 4);
                ((unsigned short*)Ps)[prow * 64 + (byteoff >> 1)] = pb[n];
            }
            #pragma unroll
            for (int n = 0; n < 4; ++n) accO[n][j] *= cr;
        }
        __syncthreads();

        #pragma unroll
        for (int kk = 0; kk < 2; ++kk) {
            int prow = wave * 16 + fr;
            bf16x8 pa = *(const bf16x8*)&Ps[prow * 64 + (((g + 4 * kk) ^ (fr & 7)) * 8)];
            #pragma unroll
            for (int n = 0; n < 4; ++n) {
                int vrow = n * 16 + fr;
                bf16x8 vb = *(const bf16x8*)&Vs[vrow * 64 + (((g + 4 * kk) ^ (fr & 7)) * 8)];
                accO[n] = __builtin_amdgcn_mfma_f32_16x16x32_bf16(pa, vb, accO[n], 0, 0, 0);
            }
        }
    }

    #pragma unroll
    for (int j = 0; j < 4; ++j) {
        float inv = 1.0f / lrun[j];
        int row = b * Tv + q0 + wave * 16 + g * 4 + j;
        #pragma unroll
        for (int n = 0; n < 4; ++n)
            att[(size_t)row * Cv + h * 64 + n * 16 + fr] =
                __float2bfloat16(accO[n][j] * inv);
    }
}

// ---------------------------------------------------------------------------
// lm-head, 256x256 tile, 8 waves (2x4), BK=64, 2-buffer phase-split schedule
// (T2 swizzle + T4 counted vmcnt + T5 setprio), fused per-block exp-sum.
// grid 1576 = 8 rowT x 197 colT, bijective XCD swizzle.
// ---------------------------------------------------------------------------
__launch_bounds__(512, 1)
__global__ void lmhead_kernel(const __hip_bfloat16* __restrict__ A,
                              const __hip_bfloat16* __restrict__ Bt,
                              float* __restrict__ Cf,
                              float* __restrict__ pLse) {
    constexpr int K = Cv, N = Vv;
    constexpr int nt = K / 64;               // 12
    __shared__ __hip_bfloat16 As[2][16384];  // [256 rows][64 k], swizzled chunks
    __shared__ __hip_bfloat16 Bs[2][16384];
    __shared__ float ps[4][256];

    int bid = blockIdx.x;
    int nid = (bid & 7) * NT2 + (bid >> 3);  // 1576 = 8*197 exact -> bijective
    int rowT = nid & 7, colT = nid >> 3;
    int rowBase = rowT * 256, colBase = colT * 256;

    int tid = threadIdx.x;
    int wv = tid >> 6, lane = tid & 63;
    int wr = wv >> 2, wc = wv & 3;           // 2 (M) x 4 (N) wave grid
    int fq = lane >> 4, fr = lane & 15;
    int fr7 = fr & 7;

    f32x4 acc[8][4] = {};

    // staging: per thread 4 A-rows + 4 B-rows, 16B chunk pre-swizzled at source
    int r8 = lane >> 3;                      // 0..7
    int cOff = ((lane & 7) ^ r8) * 8;        // swizzled chunk (elements)
    const __hip_bfloat16* ApS[4];
    const __hip_bfloat16* BpS[4];
    #pragma unroll
    for (int i = 0; i < 4; ++i) {
        int rit = wv * 32 + i * 8 + r8;      // row in tile, 0..255
        ApS[i] = A + (size_t)(rowBase + rit) * K + cOff;
        int rb = colBase + rit;
        if (rb >= N) rb = N - 1;
        BpS[i] = Bt + (size_t)rb * K + cOff;
    }

    auto stage = [&](int buf, int tile) {
        int k0 = tile * 64;
        #pragma unroll
        for (int i = 0; i < 4; ++i)
            gload16(ApS[i] + k0, &As[buf][(wv * 4 + i) * 512]);
        #pragma unroll
        for (int i = 0; i < 4; ++i)
            gload16(BpS[i] + k0, &Bs[buf][(wv * 4 + i) * 512]);
    };

    stage(0, 0);
    stage(1, 1);
    waitvm_barrier<8>();                     // tile 0 resident

    for (int t = 0; t < nt; ++t) {
        int cur = t & 1;
        const __hip_bfloat16* Ab = &As[cur][0];
        const __hip_bfloat16* Bb = &Bs[cur][0];

        // ---- phase 0: kk = 0 ----
        bf16x8 av0[8], bv0[4];
        #pragma unroll
        for (int m = 0; m < 8; ++m)
            av0[m] = *(const bf16x8*)&Ab[(wr * 128 + m * 16 + fr) * 64 + ((fq ^ fr7) * 8)];
        #pragma unroll
        for (int n = 0; n < 4; ++n)
            bv0[n] = *(const bf16x8*)&Bb[(wc * 64 + n * 16 + fr) * 64 + ((fq ^ fr7) * 8)];
        __builtin_amdgcn_s_setprio(1);
        #pragma unroll
        for (int m = 0; m < 8; ++m)
            #pragma unroll
            for (int n = 0; n < 4; ++n)
                acc[m][n] = __builtin_amdgcn_mfma_f32_16x16x32_bf16(
                    av0[m], bv0[n], acc[m][n], 0, 0, 0);
        __builtin_amdgcn_s_setprio(0);

        // ---- phase 1: kk = 1 ----
        bf16x8 av1[8], bv1[4];
        #pragma unroll
        for (int m = 0; m < 8; ++m)
            av1[m] = *(const bf16x8*)&Ab[(wr * 128 + m * 16 + fr) * 64 + (((4 + fq) ^ fr7) * 8)];
        #pragma unroll
        for (int n = 0; n < 4; ++n)
            bv1[n] = *(const bf16x8*)&Bb[(wc * 64 + n * 16 + fr) * 64 + (((4 + fq) ^ fr7) * 8)];
        lgkm0_barrier();                     // all waves done reading buf cur

        if (t + 2 < nt) stage(cur, t + 2);   // restage freed buffer

        __builtin_amdgcn_s_setprio(1);
        #pragma unroll
        for (int m = 0; m < 8; ++m)
            #pragma unroll
            for (int n = 0; n < 4; ++n)
                acc[m][n] = __builtin_amdgcn_mfma_f32_16x16x32_bf16(
                    av1[m], bv1[n], acc[m][n], 0, 0, 0);
        __builtin_amdgcn_s_setprio(0);

        if (t + 2 < nt) waitvm_barrier<8>(); // tile t+1 resident; t+2 in flight
        else            waitvm_barrier<0>();
    }

    // epilogue: store logits + per-row partial exp-sum (logits bounded ~|3.3|)
    #pragma unroll
    for (int m = 0; m < 8; ++m) {
        #pragma unroll
        for (int j = 0; j < 4; ++j) {
            int row = rowBase + wr * 128 + m * 16 + fq * 4 + j;
            float s = 0.f;
            #pragma unroll
            for (int n = 0; n < 4; ++n) {
                int col = colBase + wc * 64 + n * 16 + fr;
                float v = acc[m][n][j];
                if (col < N) {
                    Cf[(size_t)row * N + col] = v;
                    s += __expf(v);
                }
            }
            #pragma unroll
            for (int off = 1; off < 16; off <<= 1)
                s += __shfl_xor(s, off, 64);
            if (fr == 0)
                ps[wc][wr * 128 + m * 16 + fq * 4 + j] = s;
        }
    }
    __syncthreads();
    if (tid < 256)
        pLse[(size_t)(rowBase + tid) * NT2 + colT] =
            ps[0][tid] + ps[1][tid] + ps[2][tid] + ps[3][tid];
}

// ---------------------------------------------------------------------------
__global__ void plse_reduce_kernel(const float* __restrict__ pLse,
                                   const float* __restrict__ logits,
                                   const int* __restrict__ targets,
                                   float* __restrict__ rloss) {
    int row  = blockIdx.x * 4 + (threadIdx.x >> 6);
    int lane = threadIdx.x & 63;
    const float* pr = pLse + (size_t)row * NT2;
    float l = 0.f;
    for (int i = lane; i < NT2; i += 64) l += pr[i];
    #pragma unroll
    for (int off = 32; off; off >>= 1) l += __shfl_xor(l, off, 64);
    if (lane == 0)
        rloss[row] = logf(l) - logits[(size_t)row * Vv + targets[row]];
}

__global__ void loss_final_kernel(const float* __restrict__ rloss,
                                  float* __restrict__ out, int out_size) {
    float s = 0.f;
    for (int i = threadIdx.x; i < Mv; i += 256) s += rloss[i];
    #pragma unroll
    for (int off = 32; off; off >>= 1) s += __shfl_xor(s, off, 64);
    __shared__ float sw[4];
    int wave = threadIdx.x >> 6, lane = threadIdx.x & 63;
    if (lane == 0) sw[wave] = s;
    __syncthreads();
    if (threadIdx.x == 0)
        out[out_size - 1] = (sw[0] + sw[1] + sw[2] + sw[3]) / (float)Mv;
}

// ---------------------------------------------------------------------------
extern "C" void kernel_launch(void* const* d_in, const int* in_sizes, int n_in,
                              void* d_out, int out_size, void* d_ws, size_t ws_size,
                              hipStream_t stream) {
    const int*   idx     = (const int*)  d_in[0];
    const int*   targets = (const int*)  d_in[1];
    const float* wte     = (const float*)d_in[2];
    const float* wpe     = (const float*)d_in[3];
    const float* ln1_s   = (const float*)d_in[4];
    const float* ln1_b   = (const float*)d_in[5];
    const float* attn_k  = (const float*)d_in[6];
    const float* attn_b  = (const float*)d_in[7];
    const float* aproj_k = (const float*)d_in[8];
    const float* aproj_b = (const float*)d_in[9];
    const float* ln2_s   = (const float*)d_in[10];
    const float* ln2_b   = (const float*)d_in[11];
    const float* fc_k    = (const float*)d_in[12];
    const float* fc_b    = (const float*)d_in[13];
    const float* mproj_k = (const float*)d_in[14];
    const float* mproj_b = (const float*)d_in[15];
    const float* lnf_s   = (const float*)d_in[16];
    const float* lnf_b   = (const float*)d_in[17];

    float* out = (float*)d_out;
    char* ws  = (char*)d_ws;
    char* ob  = (char*)d_out;   // d_out doubles as loop-time scratch

    constexpr size_t NEED = 81962496ULL;
    if (ws_size < NEED) return;

    // ws: live through lm-head
    __hip_bfloat16* wte_bf = (__hip_bfloat16*)(ws + 0);          // 77,194,752
    __hip_bfloat16* h_bf   = (__hip_bfloat16*)(ws + 77194752);   //  3,145,728
    float*          pLse   = (float*)(ws + 80340480);            //  1,613,824
    float*          rloss  = (float*)(ws + 81954304);            //      8,192

    // d_out scratch: all dead before lmhead writes logits
    float*          x      = (float*)(ob + 0);                   //  6,291,456
    __hip_bfloat16* qkv_bf = (__hip_bfloat16*)(ob + 6291456);    //  9,437,184
    __hip_bfloat16* vt_bf  = (__hip_bfloat16*)(ob + 15728640);   //  3,145,728
    __hip_bfloat16* att_bf = (__hip_bfloat16*)(ob + 18874368);   //  3,145,728
    __hip_bfloat16* fco_bf = (__hip_bfloat16*)(ob + 22020096);   // 12,582,912
    __hip_bfloat16* w0     = (__hip_bfloat16*)(ob + 34603008);   // 14,155,776 (4 layers)
    __hip_bfloat16* w1     = (__hip_bfloat16*)(ob + 48758784);   //  4,718,592
    __hip_bfloat16* w2     = (__hip_bfloat16*)(ob + 53477376);   // 18,874,368
    __hip_bfloat16* w3     = (__hip_bfloat16*)(ob + 72351744);   // 18,874,368

    embed_kernel<<<Mv, 256, 0, stream>>>(idx, wte, wpe, x);

    // all weight transposes hoisted out of the layer loop, batched over layers
    wtrans_kernel<<<dim3(72, 24, 4), 256, 0, stream>>>(
        attn_k, w0, Cv, 2304, (size_t)Cv * 2304, (size_t)2304 * Cv);
    wtrans_kernel<<<dim3(24, 24, 4), 256, 0, stream>>>(
        aproj_k, w1, Cv, Cv, (size_t)Cv * Cv, (size_t)Cv * Cv);
    wtrans_kernel<<<dim3(96, 24, 4), 256, 0, stream>>>(
        fc_k, w2, Cv, 3072, (size_t)Cv * 3072, (size_t)3072 * Cv);
    wtrans_kernel<<<dim3(24, 96, 4), 256, 0, stream>>>(
        mproj_k, w3, 3072, Cv, (size_t)3072 * Cv, (size_t)Cv * 3072);

    for (int l = 0; l < Lv; ++l) {
        ln_kernel<<<512, 256, 0, stream>>>(x, ln1_s + l * Cv, ln1_b + l * Cv, h_bf);
        gemm_bf16<0, 128><<<dim3(36, 16), 256, 0, stream>>>(
            h_bf, w0 + (size_t)l * 2304 * Cv, attn_b + l * 2304, nullptr, nullptr,
            qkv_bf, Mv, 2304, Cv);
        vtrans_kernel<<<dim3(32, 2, 24), 256, 0, stream>>>(qkv_bf, vt_bf);
        attn_kernel<<<dim3(24, 16), 256, 0, stream>>>(qkv_bf, vt_bf, att_bf);
        gemm_bf16<1, 64><<<dim3(12, 32), 256, 0, stream>>>(
            att_bf, w1 + (size_t)l * Cv * Cv, aproj_b + l * Cv, x, x, nullptr,
            Mv, Cv, Cv);
        ln_kernel<<<512, 256, 0, stream>>>(x, ln2_s + l * Cv, ln2_b + l * Cv, h_bf);
        gemm_bf16<2, 128><<<dim3(48, 16), 256, 0, stream>>>(
            h_bf, w2 + (size_t)l * 3072 * Cv, fc_b + l * 3072, nullptr, nullptr,
            fco_bf, Mv, 3072, Cv);
        gemm_bf16<1, 64><<<dim3(12, 32), 256, 0, stream>>>(
            fco_bf, w3 + (size_t)l * Cv * 3072, mproj_b + l * Cv, x, x, nullptr,
            Mv, Cv, 3072);
    }

    ln_kernel<<<512, 256, 0, stream>>>(x, lnf_s, lnf_b, h_bf);
    cvt_kernel<<<2048, 256, 0, stream>>>(wte, wte_bf, (Vv * Cv) / 4);
    lmhead_kernel<<<8 * NT2, 512, 0, stream>>>(h_bf, wte_bf, out, pLse);
    plse_reduce_kernel<<<512, 256, 0, stream>>>(pLse, out, targets, rloss);
    loss_final_kernel<<<1, 256, 0, stream>>>(rloss, out, out_size);
}